// Round 14
// baseline (389.469 us; speedup 1.0000x reference)
//
#include <hip/hip_runtime.h>

#define N_ROWS 262144
#define DIM 64
#define KCODES 512
#define TAU_S  2.5e-3f  // score-margin flag threshold; err bound ~4e-4 -> 3x margin
#define TAU_SC 4e-3f    // scalar fallback (round-3 proven)

typedef __attribute__((ext_vector_type(8))) short bf16x8;
typedef __attribute__((ext_vector_type(4))) float f32x4;

static __device__ __forceinline__ short f2bf(float f) {   // RNE float->bf16
    union { float f; unsigned u; } c; c.f = f;
    unsigned r = (c.u + 0x7fff + ((c.u >> 16) & 1)) >> 16;
    return (short)r;
}
static __device__ __forceinline__ float bf2f(short b) {
    union { float f; unsigned u; } c;
    c.u = ((unsigned)(unsigned short)b) << 16;
    return c.f;
}

// ---- init ------------------------------------------------------------------
// eT  f32 [K][D]                       (exact output gather)
// Bc  bf16 chunk-part-LANE-LINEAR: [ch][part][lane][j] shorts, lane = q*16+n
//     part: 0=hi d0..31, 1=hi d32..63, 2=lo d0..31, 3=lo d32..63
//     -> lane l's MFMA B-fragment = 16 contiguous bytes at (l*16): coalesced
//        staging AND conflict-free ds_read_b128 (r8/r9: SQ_LDS_BANK_CONFLICT=0).
// e2h f32 [K] = -0.5*||e_k||^2 (fp64-accurate)
// e2d f64 [K] = +||e_k||^2      (exact table for the fp64 rescan; r12: saves
//     the rescan from recomputing e2 with 512 chained loads+FMAs)
__global__ void vq_init(const float* __restrict__ e, float* __restrict__ eT,
                        short* __restrict__ Bc, float* __restrict__ e2h,
                        double* __restrict__ e2d, float* __restrict__ loss_slot) {
    int idx = blockIdx.x * 256 + threadIdx.x;   // grid covers 32768
    if (idx < KCODES * DIM) {
        int k = idx >> 6, d = idx & 63;
        float v = e[d * KCODES + k];
        eT[k * DIM + d] = v;
        short hi = f2bf(v);
        short lo = f2bf(v - bf2f(hi));          // hi-residual, then RNE to bf16
        int ch = k >> 4, n = k & 15, q = (d >> 3) & 3, j = d & 7, half = d >> 5;
        int lanepos = (q * 16 + n) * 8 + j;     // lane-linear within part
        Bc[ch * 2048 + (half)     * 512 + lanepos] = hi;
        Bc[ch * 2048 + (2 + half) * 512 + lanepos] = lo;
    }
    if (idx < KCODES) {
        double s = 0.0;
        for (int d = 0; d < DIM; ++d) {
            double v = (double)e[d * KCODES + idx];
            s = fma(v, v, s);
        }
        e2h[idx] = (float)(-0.5 * s);
        e2d[idx] = s;
    }
    if (idx == 0) *loss_slot = 0.f;
}

__global__ void vq_zero_loss(float* __restrict__ loss_slot) { *loss_slot = 0.f; }

// ---- r12 lean fp64 rescan: d-outer, 8 accumulators, x loaded once per d ----
// Old form (r0-r11) was for(j)for(d): 1024 loads/lane, each fp64 FMA serially
// dependent on its own just-issued global load -> one rescan could cost
// 20-40us when load latency is exposed. New form: 576 loads/lane, 9
// independent fp64 chains (8 dots + x2) -> load latency hides under ILP.
__device__ inline void wave_rescan(const float* __restrict__ x,
                                   const float* __restrict__ e,   // [D][K]
                                   const double* __restrict__ e2d,
                                   int row, double* outDist, int* outK) {
    const int lane = threadIdx.x & 63;
    const float* xr = x + (size_t)row * DIM;
    double dot[8] = {0.0, 0.0, 0.0, 0.0, 0.0, 0.0, 0.0, 0.0};
    double x2d = 0.0;
    for (int d = 0; d < DIM; ++d) {
        double xd = (double)xr[d];               // wave-uniform broadcast
        x2d = fma(xd, xd, x2d);
        const float* er = e + d * KCODES + lane; // coalesced across lanes
        #pragma unroll
        for (int j = 0; j < 8; ++j)
            dot[j] = fma(xd, (double)er[j * 64], dot[j]);
    }
    double best = 1e300; int bk = 0;
    #pragma unroll
    for (int j = 0; j < 8; ++j) {
        const int k = lane + (j << 6);
        double dist = fma(-2.0, dot[j], x2d + e2d[k]);
        if (dist < best) { best = dist; bk = k; }   // ascending k: ties -> low k
    }
    #pragma unroll
    for (int off = 32; off; off >>= 1) {
        double od = __shfl_xor(best, off);
        int ok = __shfl_xor(bk, off);
        if (od < best || (od == best && ok < bk)) { best = od; bk = ok; }
    }
    *outDist = best; *outK = bk;
}

// old self-contained rescan (recomputes e2): used only by the no-ws fallback
__device__ inline void wave_rescan_full(const float* __restrict__ x,
                                        const float* __restrict__ e,
                                        int row, double* outDist, int* outK) {
    const int lane = threadIdx.x & 63;
    const float* xr = x + (size_t)row * DIM;
    double x2d = 0.0;
    for (int d = 0; d < DIM; ++d) {
        double xd = (double)xr[d];
        x2d = fma(xd, xd, x2d);
    }
    double best = 1e300; int bk = 0;
    for (int j = 0; j < 8; ++j) {
        const int k = lane + (j << 6);
        double dot = 0.0, e2 = 0.0;
        for (int d = 0; d < DIM; ++d) {
            double xd = (double)xr[d];
            double ev = (double)e[d * KCODES + k];
            dot = fma(xd, ev, dot);
            e2 = fma(ev, ev, e2);
        }
        double dist = fma(-2.0, dot, x2d + e2);
        if (dist < best) { best = dist; bk = k; }
    }
    #pragma unroll
    for (int off = 32; off; off >>= 1) {
        double od = __shfl_xor(best, off);
        int ok = __shfl_xor(bk, off);
        if (od < best || (od == best && ok < bk)) { best = od; bk = ok; }
    }
    *outDist = best; *outK = bk;
}

// ---- main: LDS-staged B, 2 strips/wave (32 rows) — r11 structure ----------
// r12 theory: 10 rounds of invariance (occupancy r3/r9, L2-B r8, regs r9)
// killed every hot-loop theory; per-wave lifetime is ~40us in ALL variants
// while the MFMA loop accounts for <5us. The never-varied component is the
// fp64 rescan: at TAU_S=6e-3 ~5% of rows flag -> ~80% of waves run >=1
// rescan, and the old rescan's load-chained structure could cost 20-40us
// each -> straggler waves gate the dispatch (avg concurrency 1.5 waves/SIMD:
// fast waves retire, rescanning waves linger). Fix: lean rescan (above) +
// TAU_S 6e-3 -> 2.5e-3 (err bound ~4e-4, 3x margin kept).
__global__ __launch_bounds__(512, 2) void vq_mfma(
    const float* __restrict__ x, const float* __restrict__ e,
    const float* __restrict__ eT, const short* __restrict__ Bc,
    const float* __restrict__ e2h, const double* __restrict__ e2d,
    float* __restrict__ out, float* __restrict__ loss_slot) {

    extern __shared__ __align__(16) char dynlds[];
    short* Bl = (short*)dynlds;        // 64 KB: 16 staged chunks (hi+lo)

    const int tid = threadIdx.x;       // 0..511
    const int lane = tid & 63;
    const int n = lane & 15;           // MFMA col (code within chunk) / A row
    const int q = lane >> 4;           // quad
    const int wav = tid >> 6;          // 0..7
    const int wbase = blockIdx.x * 256 + wav * 32;   // 32 rows per wave

    // 64KB pass copy: 512 thr x 8 x float4, fully coalesced
    auto stage = [&](int p) {
        const float4* src = (const float4*)Bc + p * 4096;
        float4* dst = (float4*)Bl;
        for (int i = 0; i < 8; ++i) dst[tid + i * 512] = src[tid + i * 512];
    };

    stage(0);                          // loads in flight under A-prep

    // ---- A fragments (hi/lo) + C-layout x2 for 2 strips of 16 rows ----
    bf16x8 Ah0[2], Ah1[2], Al0[2], Al1[2];
    float x2c[2][4];
    #pragma unroll
    for (int s = 0; s < 2; ++s) {
        const int row = wbase + s * 16 + n;            // A-layout row = lane&15
        const float4* xr = (const float4*)(x + (size_t)row * DIM);
        float4 f0 = xr[2*q], f1 = xr[2*q+1], f2 = xr[8+2*q], f3 = xr[9+2*q];
        float v0s[8] = {f0.x,f0.y,f0.z,f0.w,f1.x,f1.y,f1.z,f1.w};   // dims 8q..
        float v1s[8] = {f2.x,f2.y,f2.z,f2.w,f3.x,f3.y,f3.z,f3.w};   // dims 32+8q..
        float p = 0.f;
        #pragma unroll
        for (int j = 0; j < 8; ++j) {
            float v0 = v0s[j], v1 = v1s[j];
            short h0 = f2bf(v0), h1 = f2bf(v1);
            Ah0[s][j] = h0;            Ah1[s][j] = h1;
            Al0[s][j] = f2bf(v0 - bf2f(h0));
            Al1[s][j] = f2bf(v1 - bf2f(h1));
            p = fmaf(v0, v0, p);
            p = fmaf(v1, v1, p);
        }
        p += __shfl_xor(p, 16);        // lanes {n,n+16,n+32,n+48} -> full x2
        p += __shfl_xor(p, 32);
        #pragma unroll
        for (int r = 0; r < 4; ++r)    // C-layout row 4q+r held by src lane 4q+r
            x2c[s][r] = __shfl(p, 4 * q + r);
    }

    float best[2][4], sec[2][4];
    #pragma unroll
    for (int s = 0; s < 2; ++s)
        #pragma unroll
        for (int r = 0; r < 4; ++r) { best[s][r] = -3.4e38f; sec[s][r] = -3.4e38f; }

    __syncthreads();                   // pass-0 staged
    for (int p = 0; p < 2; ++p) {      // NO unroll: keep live ranges tight
        for (int c = 0; c < 16; ++c) {
            // B direct from LDS (lane-linear: conflict-free b128)
            const short* bp = Bl + c * 2048 + lane * 8;
            bf16x8 B0 = *(const bf16x8*)(bp);           // hi d0..31
            bf16x8 B1 = *(const bf16x8*)(bp + 512);     // hi d32..63
            bf16x8 B2 = *(const bf16x8*)(bp + 1024);    // lo d0..31
            bf16x8 B3 = *(const bf16x8*)(bp + 1536);    // lo d32..63
            const int ch = p * 16 + c;
            const float ev = e2h[ch * 16 + n];          // 2KB table, L1-hot
            const unsigned chid = 31u - (unsigned)ch;   // bigger = earlier chunk
            #pragma unroll
            for (int s = 0; s < 2; ++s) {
                f32x4 acc = {ev, ev, ev, ev};           // score = dot - 0.5*e2
                acc = __builtin_amdgcn_mfma_f32_16x16x32_bf16(Ah0[s], B0, acc, 0, 0, 0);
                acc = __builtin_amdgcn_mfma_f32_16x16x32_bf16(Ah1[s], B1, acc, 0, 0, 0);
                acc = __builtin_amdgcn_mfma_f32_16x16x32_bf16(Ah0[s], B2, acc, 0, 0, 0);
                acc = __builtin_amdgcn_mfma_f32_16x16x32_bf16(Ah1[s], B3, acc, 0, 0, 0);
                acc = __builtin_amdgcn_mfma_f32_16x16x32_bf16(Al0[s], B0, acc, 0, 0, 0);
                acc = __builtin_amdgcn_mfma_f32_16x16x32_bf16(Al1[s], B1, acc, 0, 0, 0);
                // lo*lo dropped: |err| ~1.4e-4, inside TAU_S margin
                #pragma unroll
                for (int r = 0; r < 4; ++r) {
                    unsigned kb = (__float_as_uint(acc[r]) & 0xFFFFFFE0u) | chid;
                    float key = __uint_as_float(kb);
                    float mn = fminf(best[s][r], key);
                    sec[s][r] = fmaxf(sec[s][r], mn);
                    best[s][r] = fmaxf(best[s][r], key);
                }
            }
        }
        if (p == 0) {
            __syncthreads();           // done reading pass-0 LDS
            stage(1);
            __syncthreads();           // pass-1 staged
        }
    }

    // ---- unpack winner, cross-lane top-2 merge over the 16 cols ----
    int kidx[2][4];
    #pragma unroll
    for (int s = 0; s < 2; ++s)
        #pragma unroll
        for (int r = 0; r < 4; ++r) {
            int ch = 31 - (int)(__float_as_uint(best[s][r]) & 31u);
            kidx[s][r] = (ch << 4) | n;
        }
    #pragma unroll
    for (int off = 1; off <= 8; off <<= 1) {
        #pragma unroll
        for (int s = 0; s < 2; ++s)
            #pragma unroll
            for (int r = 0; r < 4; ++r) {
                float ob = __shfl_xor(best[s][r], off);
                float os = __shfl_xor(sec[s][r], off);
                int   ok = __shfl_xor(kidx[s][r], off);
                float mn = fminf(best[s][r], ob);
                sec[s][r] = fmaxf(fmaxf(sec[s][r], os), mn);
                bool take = (ob > best[s][r]) || (ob == best[s][r] && ok < kidx[s][r]);
                best[s][r] = take ? ob : best[s][r];
                kidx[s][r] = take ? ok : kidx[s][r];
            }
    }

    // dist = x2 - 2*score (masked score err ~32ulp, << loss threshold)
    float lossd[2][4];
    #pragma unroll
    for (int s = 0; s < 2; ++s)
        #pragma unroll
        for (int r = 0; r < 4; ++r)
            lossd[s][r] = fmaf(-2.f, best[s][r], x2c[s][r]);

    // ---- rare fp64 certify/rescan for thin-margin rows (lean r12 form) ----
    #pragma unroll
    for (int s = 0; s < 2; ++s)
        for (int r = 0; r < 4; ++r) {
            unsigned long long m =
                __ballot((best[s][r] - sec[s][r] < TAU_S) && (n == 0));
            while (m) {
                int l = __builtin_ctzll(m);
                m &= m - 1;
                int qq = l >> 4;
                double bd; int bk;
                wave_rescan(x, e, e2d, wbase + s * 16 + 4 * qq + r, &bd, &bk);
                if (q == qq) { lossd[s][r] = (float)bd; kidx[s][r] = bk; }
            }
        }

    // ---- write quantized rows + per-wave loss atomic ----
    float lp = 0.f;
    #pragma unroll
    for (int s = 0; s < 2; ++s)
        #pragma unroll
        for (int r = 0; r < 4; ++r) {
            int row = wbase + s * 16 + 4 * q + r;
            const float4* src = (const float4*)(eT + (size_t)kidx[s][r] * DIM);
            ((float4*)(out + (size_t)row * DIM))[n] = src[n];
            if (n == 0) lp += lossd[s][r];
        }
    #pragma unroll
    for (int off = 1; off < 64; off <<= 1) lp += __shfl_xor(lp, off);
    if (lane == 0)
        atomicAdd(loss_slot, lp * (1.25f / ((float)N_ROWS * (float)DIM)));
}

// ---- fallback (no workspace): round-3 scalar kernel, 2 rows/thread ---------
__global__ __launch_bounds__(256, 2) void vq_scalar(
    const float* __restrict__ x, const float* __restrict__ e,
    float* __restrict__ out, float* __restrict__ loss_slot) {

    __shared__ float sh[128 * 68];
    __shared__ float red[256];
    const int tid = threadIdx.x;
    const int blockBase = blockIdx.x * 512;
    const int r0 = blockBase + tid, r1 = r0 + 256;

    float xa[DIM], xb[DIM];
    {
        const float4* xr0 = (const float4*)(x + (size_t)r0 * DIM);
        const float4* xr1 = (const float4*)(x + (size_t)r1 * DIM);
        #pragma unroll
        for (int j = 0; j < 16; ++j) {
            float4 v0 = xr0[j], v1 = xr1[j];
            xa[4*j]=v0.x; xa[4*j+1]=v0.y; xa[4*j+2]=v0.z; xa[4*j+3]=v0.w;
            xb[4*j]=v1.x; xb[4*j+1]=v1.y; xb[4*j+2]=v1.z; xb[4*j+3]=v1.w;
        }
    }
    float x2a = 0.f, x2b = 0.f;
    #pragma unroll
    for (int d = 0; d < DIM; ++d) { x2a = fmaf(xa[d], xa[d], x2a); x2b = fmaf(xb[d], xb[d], x2b); }

    float bestA = 3.4e38f, secA = 3.4e38f, bestB = 3.4e38f, secB = 3.4e38f;
    int bkA = 0, bkB = 0;

    for (int kb = 0; kb < KCODES; kb += 128) {
        for (int idx = tid; idx < 128 * DIM; idx += 256) {
            int d = idx >> 7, c = idx & 127;
            sh[c * 68 + d] = e[d * KCODES + kb + c];
        }
        __syncthreads();
        if (tid < 128) {
            float ssum = 0.f;
            for (int d = 0; d < DIM; ++d) { float v = sh[tid * 68 + d]; ssum = fmaf(v, v, ssum); }
            sh[tid * 68 + 64] = ssum;
        }
        __syncthreads();
        for (int k = 0; k < 128; ++k) {
            const float* ck = sh + k * 68;
            float a0=0.f,a1=0.f,b0=0.f,b1=0.f;
            #pragma unroll
            for (int j = 0; j < 16; j += 2) {
                float4 c0 = *(const float4*)(ck + 4*j);
                float4 c1 = *(const float4*)(ck + 4*j + 4);
                a0=fmaf(xa[4*j],c0.x,a0); a0=fmaf(xa[4*j+1],c0.y,a0); a0=fmaf(xa[4*j+2],c0.z,a0); a0=fmaf(xa[4*j+3],c0.w,a0);
                b0=fmaf(xb[4*j],c0.x,b0); b0=fmaf(xb[4*j+1],c0.y,b0); b0=fmaf(xb[4*j+2],c0.z,b0); b0=fmaf(xb[4*j+3],c0.w,b0);
                a1=fmaf(xa[4*j+4],c1.x,a1); a1=fmaf(xa[4*j+5],c1.y,a1); a1=fmaf(xa[4*j+6],c1.z,a1); a1=fmaf(xa[4*j+7],c1.w,a1);
                b1=fmaf(xb[4*j+4],c1.x,b1); b1=fmaf(xb[4*j+5],c1.y,b1); b1=fmaf(xb[4*j+6],c1.z,b1); b1=fmaf(xb[4*j+7],c1.w,b1);
            }
            const float e2k = ck[64]; const int kg = kb + k;
            const float dA = fmaf(-2.f, a0 + a1, x2a + e2k);
            const float dB = fmaf(-2.f, b0 + b1, x2b + e2k);
            if (dA < bestA) { secA = bestA; bestA = dA; bkA = kg; } else if (dA < secA) secA = dA;
            if (dB < bestB) { secB = bestB; bestB = dB; bkB = kg; } else if (dB < secB) secB = dB;
        }
        __syncthreads();
    }

    const int lane = tid & 63;
    const int waveBase = blockBase + (tid & ~63);
    unsigned long long m = __ballot(secA - bestA < TAU_SC);
    while (m) {
        int l = __builtin_ctzll(m); m &= m - 1;
        double bd; int bk2;
        wave_rescan_full(x, e, waveBase + l, &bd, &bk2);
        if (lane == l) { bestA = (float)bd; bkA = bk2; }
    }
    m = __ballot(secB - bestB < TAU_SC);
    while (m) {
        int l = __builtin_ctzll(m); m &= m - 1;
        double bd; int bk2;
        wave_rescan_full(x, e, waveBase + 256 + l, &bd, &bk2);
        if (lane == l) { bestB = (float)bd; bkB = bk2; }
    }

    float4* o0 = (float4*)(out + (size_t)r0 * DIM);
    float4* o1 = (float4*)(out + (size_t)r1 * DIM);
    #pragma unroll
    for (int j = 0; j < 16; ++j) {
        float4 va, vb;
        va.x=e[(4*j)*KCODES+bkA]; vb.x=e[(4*j)*KCODES+bkB];
        va.y=e[(4*j+1)*KCODES+bkA]; vb.y=e[(4*j+1)*KCODES+bkB];
        va.z=e[(4*j+2)*KCODES+bkA]; vb.z=e[(4*j+2)*KCODES+bkB];
        va.w=e[(4*j+3)*KCODES+bkA]; vb.w=e[(4*j+3)*KCODES+bkB];
        o0[j]=va; o1[j]=vb;
    }

    red[tid] = bestA + bestB;
    __syncthreads();
    #pragma unroll
    for (int s2 = 128; s2 > 0; s2 >>= 1) {
        if (tid < s2) red[tid] += red[tid + s2];
        __syncthreads();
    }
    if (tid == 0) atomicAdd(loss_slot, red[0] * (1.25f / ((float)N_ROWS * (float)DIM)));
}

extern "C" void kernel_launch(void* const* d_in, const int* in_sizes, int n_in,
                              void* d_out, int out_size, void* d_ws, size_t ws_size,
                              hipStream_t stream) {
    const float* x = (const float*)d_in[0];   // [N, D]
    const float* e = (const float*)d_in[1];   // [D, K]
    float* out = (float*)d_out;               // N*D quantized + 1 loss
    float* loss_slot = out + (size_t)N_ROWS * DIM;

    // ws: eT f32 @0 (131072) | Bc bf16 @131072 (131072) | e2h @262144 (2048)
    //     | e2d f64 @264192 (4096)
    const size_t ws_needed = 131072 + 131072 + 2048 + 4096;

    if (ws_size >= ws_needed) {
        float* eT = (float*)d_ws;
        short* Bc = (short*)((char*)d_ws + 131072);
        float* e2h = (float*)((char*)d_ws + 262144);
        double* e2d = (double*)((char*)d_ws + 264192);
        vq_init<<<128, 256, 0, stream>>>(e, eT, Bc, e2h, e2d, loss_slot);
        // 1024 blocks x 512 thr, 256 rows/block; 64 KB dynamic LDS (default limit)
        vq_mfma<<<N_ROWS / 256, 512, 65536, stream>>>(x, e, eT, Bc, e2h, e2d, out, loss_slot);
    } else {
        vq_zero_loss<<<1, 1, 0, stream>>>(loss_slot);
        vq_scalar<<<N_ROWS / 512, 256, 0, stream>>>(x, e, out, loss_slot);
    }
}

// Round 16
// 232.140 us; speedup vs baseline: 1.6777x; 1.6777x over previous
//
#include <hip/hip_runtime.h>

#define N_ROWS 262144
#define DIM 64
#define KCODES 512
#define TAU_S  2.5e-3f  // r15: single change vs r0 (was 6e-3). Err bound ~4e-4
                        // (lo*lo drop 1.4e-4 + f32 accum + 32-ulp mask) -> 6x
                        // margin; 2.5e-3 field-proven correct in r12's run.
#define TAU_SC 4e-3f    // scalar fallback (round-3 proven)

typedef __attribute__((ext_vector_type(8))) short bf16x8;
typedef __attribute__((ext_vector_type(4))) float f32x4;

static __device__ __forceinline__ short f2bf(float f) {   // RNE float->bf16
    union { float f; unsigned u; } c; c.f = f;
    unsigned r = (c.u + 0x7fff + ((c.u >> 16) & 1)) >> 16;
    return (short)r;
}
static __device__ __forceinline__ float bf2f(short b) {
    union { float f; unsigned u; } c;
    c.u = ((unsigned)(unsigned short)b) << 16;
    return c.f;
}

// ---- init ------------------------------------------------------------------
// eT  f32 [K][D]                       (exact output gather)
// Bc  bf16 chunk-part-major: [ch][part][n][q][j] shorts,
//     part: 0=hi d0..31, 1=hi d32..63, 2=lo d0..31, 3=lo d32..63
//     index = ch*2048 + part*512 + n*32 + q*8 + j   (per-part wave load = 1KB contig)
// e2h f32 [K] = -0.5*||e_k||^2 (fp64-accurate)
__global__ void vq_init(const float* __restrict__ e, float* __restrict__ eT,
                        short* __restrict__ Bc, float* __restrict__ e2h,
                        float* __restrict__ loss_slot) {
    int idx = blockIdx.x * 256 + threadIdx.x;   // grid covers 32768
    if (idx < KCODES * DIM) {
        int k = idx >> 6, d = idx & 63;
        float v = e[d * KCODES + k];
        eT[k * DIM + d] = v;
        short hi = f2bf(v);
        short lo = f2bf(v - bf2f(hi));          // hi-residual, then RNE to bf16
        int ch = k >> 4, n = k & 15, q = (d >> 3) & 3, j = d & 7, half = d >> 5;
        Bc[ch * 2048 + (half)     * 512 + n * 32 + q * 8 + j] = hi;
        Bc[ch * 2048 + (2 + half) * 512 + n * 32 + q * 8 + j] = lo;
    }
    if (idx < KCODES) {
        double s = 0.0;
        for (int d = 0; d < DIM; ++d) {
            double v = (double)e[d * KCODES + idx];
            s = fma(v, v, s);
        }
        e2h[idx] = (float)(-0.5 * s);
    }
    if (idx == 0) *loss_slot = 0.f;
}

__global__ void vq_zero_loss(float* __restrict__ loss_slot) { *loss_slot = 0.f; }

// ---- wave-cooperative exact fp64 rescan of one row (all 64 lanes call) -----
__device__ inline void wave_rescan(const float* __restrict__ x,
                                   const float* __restrict__ e,  // [D][K]
                                   int row, double* outDist, int* outK) {
    const int lane = threadIdx.x & 63;
    const float* xr = x + (size_t)row * DIM;
    double x2d = 0.0;
    for (int d = 0; d < DIM; ++d) {
        double xd = (double)xr[d];
        x2d = fma(xd, xd, x2d);
    }
    double best = 1e300; int bk = 0;
    for (int j = 0; j < 8; ++j) {
        const int k = lane + (j << 6);
        double dot = 0.0, e2 = 0.0;
        for (int d = 0; d < DIM; ++d) {
            double xd = (double)xr[d];
            double ev = (double)e[d * KCODES + k];
            dot = fma(xd, ev, dot);
            e2 = fma(ev, ev, e2);
        }
        double dist = fma(-2.0, dot, x2d + e2);
        if (dist < best) { best = dist; bk = k; }
    }
    #pragma unroll
    for (int off = 32; off; off >>= 1) {
        double od = __shfl_xor(best, off);
        int ok = __shfl_xor(bk, off);
        if (od < best || (od == best && ok < bk)) { best = od; bk = ok; }
    }
    *outDist = best; *outK = bk;
}

// ---- main: 64 rows/wave, global-B ping-pong, no hot-loop barriers ----------
// r15: EXACT revert to the r0 kernel (best measured: vq_mfma 176us, harness
// 246us) with ONE variable changed: TAU_S 6e-3 -> 2.5e-3. Rationale: the
// whole grid is co-resident (1024 blocks <= 4/CU), so dispatch dur = slowest
// wave (~4x the 42us mean lifetime) -> straggler tail. Only per-wave-variable
// work is the rescan count (~3 mean / ~12 max per wave at 6e-3). 2.4x fewer
// flags shrinks the max-wave tail if that theory holds; if null, we are at
// the structural floor (r3/r8/r9/r12 all measured worse: occupancy, LDS-B,
// reg-fit, lean-rescan every theory falsified).
__global__ __launch_bounds__(256, 2) void vq_mfma(
    const float* __restrict__ x, const float* __restrict__ e,
    const float* __restrict__ eT, const short* __restrict__ Bc,
    const float* __restrict__ e2h,
    float* __restrict__ out, float* __restrict__ loss_slot) {

    __shared__ float she2[KCODES];     // 2 KB: -0.5*e2, staged once

    const int tid = threadIdx.x;
    const int lane = tid & 63;
    const int n = lane & 15;           // MFMA col (code within chunk) / A row
    const int q = lane >> 4;           // quad
    const int wav = tid >> 6;          // 0..3
    const int wbase = blockIdx.x * 256 + wav * 64;   // 64 rows per wave

    for (int i = tid; i < KCODES; i += 256) she2[i] = e2h[i];
    __syncthreads();                   // only barrier in the kernel

    // ---- A fragments (hi/lo) + C-layout x2 for 4 strips of 16 rows ----
    bf16x8 Ah0[4], Ah1[4], Al0[4], Al1[4];
    float x2c[4][4];
    #pragma unroll
    for (int s = 0; s < 4; ++s) {
        const int row = wbase + s * 16 + n;            // A-layout row = lane&15
        const float4* xr = (const float4*)(x + (size_t)row * DIM);
        float4 f0 = xr[2*q], f1 = xr[2*q+1], f2 = xr[8+2*q], f3 = xr[9+2*q];
        float v0s[8] = {f0.x,f0.y,f0.z,f0.w,f1.x,f1.y,f1.z,f1.w};   // dims 8q..
        float v1s[8] = {f2.x,f2.y,f2.z,f2.w,f3.x,f3.y,f3.z,f3.w};   // dims 32+8q..
        float p = 0.f;
        #pragma unroll
        for (int j = 0; j < 8; ++j) {
            float v0 = v0s[j], v1 = v1s[j];
            short h0 = f2bf(v0), h1 = f2bf(v1);
            Ah0[s][j] = h0;            Ah1[s][j] = h1;
            Al0[s][j] = f2bf(v0 - bf2f(h0));
            Al1[s][j] = f2bf(v1 - bf2f(h1));
            p = fmaf(v0, v0, p);
            p = fmaf(v1, v1, p);
        }
        p += __shfl_xor(p, 16);        // lanes {n,n+16,n+32,n+48} -> full x2
        p += __shfl_xor(p, 32);
        #pragma unroll
        for (int r = 0; r < 4; ++r)    // C-layout row 4q+r held by src lane 4q+r
            x2c[s][r] = __shfl(p, 4 * q + r);
    }

    float best[4][4], sec[4][4];
    #pragma unroll
    for (int s = 0; s < 4; ++s)
        #pragma unroll
        for (int r = 0; r < 4; ++r) { best[s][r] = -3.4e38f; sec[s][r] = -3.4e38f; }

    bf16x8 Ba[4], Bb[4];
    float ea, eb;

    auto loadB = [&](bf16x8* Bf, float& ev, int ch) {
        const short* bp = Bc + ch * 2048 + n * 32 + q * 8;
        Bf[0] = *(const bf16x8*)(bp);           // hi d0..31  (k = 8q+j)
        Bf[1] = *(const bf16x8*)(bp + 512);     // hi d32..63
        Bf[2] = *(const bf16x8*)(bp + 1024);    // lo d0..31
        Bf[3] = *(const bf16x8*)(bp + 1536);    // lo d32..63
        ev = she2[ch * 16 + n];                 // -0.5*e2 (16 banks, broadcast)
    };

    auto proc = [&](const bf16x8* Bf, float ev, int ch) {
        const unsigned chid = 31u - (unsigned)ch;   // bigger = earlier chunk
        #pragma unroll
        for (int s = 0; s < 4; ++s) {
            f32x4 acc = {ev, ev, ev, ev};           // score = dot - 0.5*e2
            acc = __builtin_amdgcn_mfma_f32_16x16x32_bf16(Ah0[s], Bf[0], acc, 0, 0, 0);
            acc = __builtin_amdgcn_mfma_f32_16x16x32_bf16(Ah1[s], Bf[1], acc, 0, 0, 0);
            acc = __builtin_amdgcn_mfma_f32_16x16x32_bf16(Ah0[s], Bf[2], acc, 0, 0, 0);
            acc = __builtin_amdgcn_mfma_f32_16x16x32_bf16(Ah1[s], Bf[3], acc, 0, 0, 0);
            acc = __builtin_amdgcn_mfma_f32_16x16x32_bf16(Al0[s], Bf[0], acc, 0, 0, 0);
            acc = __builtin_amdgcn_mfma_f32_16x16x32_bf16(Al1[s], Bf[1], acc, 0, 0, 0);
            // lo*lo dropped: |err| ~1e-4 << TAU_S, certified below
            #pragma unroll
            for (int r = 0; r < 4; ++r) {
                unsigned kb = (__float_as_uint(acc[r]) & 0xFFFFFFE0u) | chid;
                float key = __uint_as_float(kb);
                float mn = fminf(best[s][r], key);
                sec[s][r] = fmaxf(sec[s][r], mn);
                best[s][r] = fmaxf(best[s][r], key);
            }
        }
    };

    // ping-pong global (L2-hot) prefetch over 32 chunks of 16 codes
    loadB(Ba, ea, 0);
    for (int ch = 0; ch < 32; ch += 2) {
        loadB(Bb, eb, ch + 1);
        proc(Ba, ea, ch);
        if (ch + 2 < 32) loadB(Ba, ea, ch + 2);
        proc(Bb, eb, ch + 1);
    }

    // ---- unpack winner, cross-lane top-2 merge over the 16 cols ----
    int kidx[4][4];
    #pragma unroll
    for (int s = 0; s < 4; ++s)
        #pragma unroll
        for (int r = 0; r < 4; ++r) {
            int ch = 31 - (int)(__float_as_uint(best[s][r]) & 31u);
            kidx[s][r] = (ch << 4) | n;
        }
    #pragma unroll
    for (int off = 1; off <= 8; off <<= 1) {
        #pragma unroll
        for (int s = 0; s < 4; ++s)
            #pragma unroll
            for (int r = 0; r < 4; ++r) {
                float ob = __shfl_xor(best[s][r], off);
                float os = __shfl_xor(sec[s][r], off);
                int   ok = __shfl_xor(kidx[s][r], off);
                float mn = fminf(best[s][r], ob);
                sec[s][r] = fmaxf(fmaxf(sec[s][r], os), mn);
                bool take = (ob > best[s][r]) || (ob == best[s][r] && ok < kidx[s][r]);
                best[s][r] = take ? ob : best[s][r];
                kidx[s][r] = take ? ok : kidx[s][r];
            }
    }

    // dist = x2 - 2*score (masked score err ~32ulp, << loss threshold)
    float lossd[4][4];
    #pragma unroll
    for (int s = 0; s < 4; ++s)
        #pragma unroll
        for (int r = 0; r < 4; ++r)
            lossd[s][r] = fmaf(-2.f, best[s][r], x2c[s][r]);

    // ---- rare fp64 certify/rescan for thin-margin rows ----
    #pragma unroll
    for (int s = 0; s < 4; ++s)
        for (int r = 0; r < 4; ++r) {
            unsigned long long m =
                __ballot((best[s][r] - sec[s][r] < TAU_S) && (n == 0));
            while (m) {
                int l = __builtin_ctzll(m);
                m &= m - 1;
                int qq = l >> 4;
                double bd; int bk;
                wave_rescan(x, e, wbase + s * 16 + 4 * qq + r, &bd, &bk);
                if (q == qq) { lossd[s][r] = (float)bd; kidx[s][r] = bk; }
            }
        }

    // ---- write quantized rows + loss ----
    float lp = 0.f;
    #pragma unroll
    for (int s = 0; s < 4; ++s)
        #pragma unroll
        for (int r = 0; r < 4; ++r) {
            int row = wbase + s * 16 + 4 * q + r;
            const float4* src = (const float4*)(eT + (size_t)kidx[s][r] * DIM);
            ((float4*)(out + (size_t)row * DIM))[n] = src[n];
            if (n == 0) lp += lossd[s][r];
        }
    #pragma unroll
    for (int off = 1; off < 64; off <<= 1) lp += __shfl_xor(lp, off);
    if (lane == 0)
        atomicAdd(loss_slot, lp * (1.25f / ((float)N_ROWS * (float)DIM)));
}

// ---- fallback (no workspace): round-3 scalar kernel, 2 rows/thread ---------
__global__ __launch_bounds__(256, 2) void vq_scalar(
    const float* __restrict__ x, const float* __restrict__ e,
    float* __restrict__ out, float* __restrict__ loss_slot) {

    __shared__ float sh[128 * 68];
    __shared__ float red[256];
    const int tid = threadIdx.x;
    const int blockBase = blockIdx.x * 512;
    const int r0 = blockBase + tid, r1 = r0 + 256;

    float xa[DIM], xb[DIM];
    {
        const float4* xr0 = (const float4*)(x + (size_t)r0 * DIM);
        const float4* xr1 = (const float4*)(x + (size_t)r1 * DIM);
        #pragma unroll
        for (int j = 0; j < 16; ++j) {
            float4 v0 = xr0[j], v1 = xr1[j];
            xa[4*j]=v0.x; xa[4*j+1]=v0.y; xa[4*j+2]=v0.z; xa[4*j+3]=v0.w;
            xb[4*j]=v1.x; xb[4*j+1]=v1.y; xb[4*j+2]=v1.z; xb[4*j+3]=v1.w;
        }
    }
    float x2a = 0.f, x2b = 0.f;
    #pragma unroll
    for (int d = 0; d < DIM; ++d) { x2a = fmaf(xa[d], xa[d], x2a); x2b = fmaf(xb[d], xb[d], x2b); }

    float bestA = 3.4e38f, secA = 3.4e38f, bestB = 3.4e38f, secB = 3.4e38f;
    int bkA = 0, bkB = 0;

    for (int kb = 0; kb < KCODES; kb += 128) {
        for (int idx = tid; idx < 128 * DIM; idx += 256) {
            int d = idx >> 7, c = idx & 127;
            sh[c * 68 + d] = e[d * KCODES + kb + c];
        }
        __syncthreads();
        if (tid < 128) {
            float ssum = 0.f;
            for (int d = 0; d < DIM; ++d) { float v = sh[tid * 68 + d]; ssum = fmaf(v, v, ssum); }
            sh[tid * 68 + 64] = ssum;
        }
        __syncthreads();
        for (int k = 0; k < 128; ++k) {
            const float* ck = sh + k * 68;
            float a0=0.f,a1=0.f,b0=0.f,b1=0.f;
            #pragma unroll
            for (int j = 0; j < 16; j += 2) {
                float4 c0 = *(const float4*)(ck + 4*j);
                float4 c1 = *(const float4*)(ck + 4*j + 4);
                a0=fmaf(xa[4*j],c0.x,a0); a0=fmaf(xa[4*j+1],c0.y,a0); a0=fmaf(xa[4*j+2],c0.z,a0); a0=fmaf(xa[4*j+3],c0.w,a0);
                b0=fmaf(xb[4*j],c0.x,b0); b0=fmaf(xb[4*j+1],c0.y,b0); b0=fmaf(xb[4*j+2],c0.z,b0); b0=fmaf(xb[4*j+3],c0.w,b0);
                a1=fmaf(xa[4*j+4],c1.x,a1); a1=fmaf(xa[4*j+5],c1.y,a1); a1=fmaf(xa[4*j+6],c1.z,a1); a1=fmaf(xa[4*j+7],c1.w,a1);
                b1=fmaf(xb[4*j+4],c1.x,b1); b1=fmaf(xb[4*j+5],c1.y,b1); b1=fmaf(xb[4*j+6],c1.z,b1); b1=fmaf(xb[4*j+7],c1.w,b1);
            }
            const float e2k = ck[64]; const int kg = kb + k;
            const float dA = fmaf(-2.f, a0 + a1, x2a + e2k);
            const float dB = fmaf(-2.f, b0 + b1, x2b + e2k);
            if (dA < bestA) { secA = bestA; bestA = dA; bkA = kg; } else if (dA < secA) secA = dA;
            if (dB < bestB) { secB = bestB; bestB = dB; bkB = kg; } else if (dB < secB) secB = dB;
        }
        __syncthreads();
    }

    const int lane = tid & 63;
    const int waveBase = blockBase + (tid & ~63);
    unsigned long long m = __ballot(secA - bestA < TAU_SC);
    while (m) {
        int l = __builtin_ctzll(m); m &= m - 1;
        double bd; int bk2;
        wave_rescan(x, e, waveBase + l, &bd, &bk2);
        if (lane == l) { bestA = (float)bd; bkA = bk2; }
    }
    m = __ballot(secB - bestB < TAU_SC);
    while (m) {
        int l = __builtin_ctzll(m); m &= m - 1;
        double bd; int bk2;
        wave_rescan(x, e, waveBase + 256 + l, &bd, &bk2);
        if (lane == l) { bestB = (float)bd; bkB = bk2; }
    }

    float4* o0 = (float4*)(out + (size_t)r0 * DIM);
    float4* o1 = (float4*)(out + (size_t)r1 * DIM);
    #pragma unroll
    for (int j = 0; j < 16; ++j) {
        float4 va, vb;
        va.x=e[(4*j)*KCODES+bkA]; vb.x=e[(4*j)*KCODES+bkB];
        va.y=e[(4*j+1)*KCODES+bkA]; vb.y=e[(4*j+1)*KCODES+bkB];
        va.z=e[(4*j+2)*KCODES+bkA]; vb.z=e[(4*j+2)*KCODES+bkB];
        va.w=e[(4*j+3)*KCODES+bkA]; vb.w=e[(4*j+3)*KCODES+bkB];
        o0[j]=va; o1[j]=vb;
    }

    red[tid] = bestA + bestB;
    __syncthreads();
    #pragma unroll
    for (int s2 = 128; s2 > 0; s2 >>= 1) {
        if (tid < s2) red[tid] += red[tid + s2];
        __syncthreads();
    }
    if (tid == 0) atomicAdd(loss_slot, red[0] * (1.25f / ((float)N_ROWS * (float)DIM)));
}

extern "C" void kernel_launch(void* const* d_in, const int* in_sizes, int n_in,
                              void* d_out, int out_size, void* d_ws, size_t ws_size,
                              hipStream_t stream) {
    const float* x = (const float*)d_in[0];   // [N, D]
    const float* e = (const float*)d_in[1];   // [D, K]
    float* out = (float*)d_out;               // N*D quantized + 1 loss
    float* loss_slot = out + (size_t)N_ROWS * DIM;

    // ws: eT f32 @0 (131072) | Bc bf16 @131072 (131072) | e2h @262144 (2048)
    const size_t ws_needed = 131072 + 131072 + 2048;

    if (ws_size >= ws_needed) {
        float* eT = (float*)d_ws;
        short* Bc = (short*)((char*)d_ws + 131072);
        float* e2h = (float*)((char*)d_ws + 262144);
        vq_init<<<128, 256, 0, stream>>>(e, eT, Bc, e2h, loss_slot);
        vq_mfma<<<N_ROWS / 256, 256, 0, stream>>>(x, e, eT, Bc, e2h, out, loss_slot);
    } else {
        vq_zero_loss<<<1, 1, 0, stream>>>(loss_slot);
        vq_scalar<<<N_ROWS / 512, 256, 0, stream>>>(x, e, out, loss_slot);
    }
}

// Round 17
// 222.123 us; speedup vs baseline: 1.7534x; 1.0451x over previous
//
#include <hip/hip_runtime.h>

#define N_ROWS 262144
#define DIM 64
#define KCODES 512
#define TAU_S  2.5e-3f  // r15-proven: err bound ~5e-4 -> ~5x margin; field-proven
#define TAU_SC 4e-3f    // scalar fallback (round-3 proven)

typedef __attribute__((ext_vector_type(8))) short bf16x8;
typedef __attribute__((ext_vector_type(4))) float f32x4;

static __device__ __forceinline__ short f2bf(float f) {   // RNE float->bf16
    union { float f; unsigned u; } c; c.f = f;
    unsigned r = (c.u + 0x7fff + ((c.u >> 16) & 1)) >> 16;
    return (short)r;
}
static __device__ __forceinline__ float bf2f(short b) {
    union { float f; unsigned u; } c;
    c.u = ((unsigned)(unsigned short)b) << 16;
    return c.f;
}

// ---- init ------------------------------------------------------------------
// eT  f32 [K][D]                       (exact output gather)
// Bc  bf16 chunk-part-major: [ch][part][n][q][j] shorts,
//     part: 0=hi d0..31, 1=hi d32..63, 2=lo d0..31, 3=lo d32..63
//     index = ch*2048 + part*512 + n*32 + q*8 + j   (per-part wave load = 1KB contig)
// e2h f32 [K] = -0.5*||e_k||^2 (fp64-accurate)
__global__ void vq_init(const float* __restrict__ e, float* __restrict__ eT,
                        short* __restrict__ Bc, float* __restrict__ e2h,
                        float* __restrict__ loss_slot) {
    int idx = blockIdx.x * 256 + threadIdx.x;   // grid covers 32768
    if (idx < KCODES * DIM) {
        int k = idx >> 6, d = idx & 63;
        float v = e[d * KCODES + k];
        eT[k * DIM + d] = v;
        short hi = f2bf(v);
        short lo = f2bf(v - bf2f(hi));          // hi-residual, then RNE to bf16
        int ch = k >> 4, n = k & 15, q = (d >> 3) & 3, j = d & 7, half = d >> 5;
        Bc[ch * 2048 + (half)     * 512 + n * 32 + q * 8 + j] = hi;
        Bc[ch * 2048 + (2 + half) * 512 + n * 32 + q * 8 + j] = lo;
    }
    if (idx < KCODES) {
        double s = 0.0;
        for (int d = 0; d < DIM; ++d) {
            double v = (double)e[d * KCODES + idx];
            s = fma(v, v, s);
        }
        e2h[idx] = (float)(-0.5 * s);
    }
    if (idx == 0) *loss_slot = 0.f;
}

__global__ void vq_zero_loss(float* __restrict__ loss_slot) { *loss_slot = 0.f; }

// ---- wave-cooperative exact fp64 rescan of one row (all 64 lanes call) -----
__device__ inline void wave_rescan(const float* __restrict__ x,
                                   const float* __restrict__ e,  // [D][K]
                                   int row, double* outDist, int* outK) {
    const int lane = threadIdx.x & 63;
    const float* xr = x + (size_t)row * DIM;
    double x2d = 0.0;
    for (int d = 0; d < DIM; ++d) {
        double xd = (double)xr[d];
        x2d = fma(xd, xd, x2d);
    }
    double best = 1e300; int bk = 0;
    for (int j = 0; j < 8; ++j) {
        const int k = lane + (j << 6);
        double dot = 0.0, e2 = 0.0;
        for (int d = 0; d < DIM; ++d) {
            double xd = (double)xr[d];
            double ev = (double)e[d * KCODES + k];
            dot = fma(xd, ev, dot);
            e2 = fma(ev, ev, e2);
        }
        double dist = fma(-2.0, dot, x2d + e2);
        if (dist < best) { best = dist; bk = k; }
    }
    #pragma unroll
    for (int off = 32; off; off >>= 1) {
        double od = __shfl_xor(best, off);
        int ok = __shfl_xor(bk, off);
        if (od < best || (od == best && ok < bk)) { best = od; bk = ok; }
    }
    *outDist = best; *outK = bk;
}

// ---- main: 64 rows/wave, global-B ping-pong, no hot-loop barriers ----------
// r17: r15 winner (161us kernel / 232us harness, best measured) + ONE change:
// per-wave atomicAdd (4096 same-address atomics) -> per-block LDS reduce +
// one atomic (1024). Theory: waves in a block-generation finish nearly
// simultaneously -> burst of ~1024 serialized same-address L2 atomics per
// generation (~15-30us queue); a wave can't retire until its atomic lands,
// so the drain gates generation turnover. Occupancy/L2/reg-invariant --
// matches the residual profile. If null: practical floor by exhaustion.
__global__ __launch_bounds__(256, 2) void vq_mfma(
    const float* __restrict__ x, const float* __restrict__ e,
    const float* __restrict__ eT, const short* __restrict__ Bc,
    const float* __restrict__ e2h,
    float* __restrict__ out, float* __restrict__ loss_slot) {

    __shared__ float she2[KCODES];     // 2 KB: -0.5*e2, staged once
    __shared__ float lred[4];          // r17: per-wave loss partials

    const int tid = threadIdx.x;
    const int lane = tid & 63;
    const int n = lane & 15;           // MFMA col (code within chunk) / A row
    const int q = lane >> 4;           // quad
    const int wav = tid >> 6;          // 0..3
    const int wbase = blockIdx.x * 256 + wav * 64;   // 64 rows per wave

    for (int i = tid; i < KCODES; i += 256) she2[i] = e2h[i];
    __syncthreads();

    // ---- A fragments (hi/lo) + C-layout x2 for 4 strips of 16 rows ----
    bf16x8 Ah0[4], Ah1[4], Al0[4], Al1[4];
    float x2c[4][4];
    #pragma unroll
    for (int s = 0; s < 4; ++s) {
        const int row = wbase + s * 16 + n;            // A-layout row = lane&15
        const float4* xr = (const float4*)(x + (size_t)row * DIM);
        float4 f0 = xr[2*q], f1 = xr[2*q+1], f2 = xr[8+2*q], f3 = xr[9+2*q];
        float v0s[8] = {f0.x,f0.y,f0.z,f0.w,f1.x,f1.y,f1.z,f1.w};   // dims 8q..
        float v1s[8] = {f2.x,f2.y,f2.z,f2.w,f3.x,f3.y,f3.z,f3.w};   // dims 32+8q..
        float p = 0.f;
        #pragma unroll
        for (int j = 0; j < 8; ++j) {
            float v0 = v0s[j], v1 = v1s[j];
            short h0 = f2bf(v0), h1 = f2bf(v1);
            Ah0[s][j] = h0;            Ah1[s][j] = h1;
            Al0[s][j] = f2bf(v0 - bf2f(h0));
            Al1[s][j] = f2bf(v1 - bf2f(h1));
            p = fmaf(v0, v0, p);
            p = fmaf(v1, v1, p);
        }
        p += __shfl_xor(p, 16);        // lanes {n,n+16,n+32,n+48} -> full x2
        p += __shfl_xor(p, 32);
        #pragma unroll
        for (int r = 0; r < 4; ++r)    // C-layout row 4q+r held by src lane 4q+r
            x2c[s][r] = __shfl(p, 4 * q + r);
    }

    float best[4][4], sec[4][4];
    #pragma unroll
    for (int s = 0; s < 4; ++s)
        #pragma unroll
        for (int r = 0; r < 4; ++r) { best[s][r] = -3.4e38f; sec[s][r] = -3.4e38f; }

    bf16x8 Ba[4], Bb[4];
    float ea, eb;

    auto loadB = [&](bf16x8* Bf, float& ev, int ch) {
        const short* bp = Bc + ch * 2048 + n * 32 + q * 8;
        Bf[0] = *(const bf16x8*)(bp);           // hi d0..31  (k = 8q+j)
        Bf[1] = *(const bf16x8*)(bp + 512);     // hi d32..63
        Bf[2] = *(const bf16x8*)(bp + 1024);    // lo d0..31
        Bf[3] = *(const bf16x8*)(bp + 1536);    // lo d32..63
        ev = she2[ch * 16 + n];                 // -0.5*e2 (16 banks, broadcast)
    };

    auto proc = [&](const bf16x8* Bf, float ev, int ch) {
        const unsigned chid = 31u - (unsigned)ch;   // bigger = earlier chunk
        #pragma unroll
        for (int s = 0; s < 4; ++s) {
            f32x4 acc = {ev, ev, ev, ev};           // score = dot - 0.5*e2
            acc = __builtin_amdgcn_mfma_f32_16x16x32_bf16(Ah0[s], Bf[0], acc, 0, 0, 0);
            acc = __builtin_amdgcn_mfma_f32_16x16x32_bf16(Ah1[s], Bf[1], acc, 0, 0, 0);
            acc = __builtin_amdgcn_mfma_f32_16x16x32_bf16(Ah0[s], Bf[2], acc, 0, 0, 0);
            acc = __builtin_amdgcn_mfma_f32_16x16x32_bf16(Ah1[s], Bf[3], acc, 0, 0, 0);
            acc = __builtin_amdgcn_mfma_f32_16x16x32_bf16(Al0[s], Bf[0], acc, 0, 0, 0);
            acc = __builtin_amdgcn_mfma_f32_16x16x32_bf16(Al1[s], Bf[1], acc, 0, 0, 0);
            // lo*lo dropped: |err| ~1e-4 << TAU_S, certified below
            #pragma unroll
            for (int r = 0; r < 4; ++r) {
                unsigned kb = (__float_as_uint(acc[r]) & 0xFFFFFFE0u) | chid;
                float key = __uint_as_float(kb);
                float mn = fminf(best[s][r], key);
                sec[s][r] = fmaxf(sec[s][r], mn);
                best[s][r] = fmaxf(best[s][r], key);
            }
        }
    };

    // ping-pong global (L2-hot) prefetch over 32 chunks of 16 codes
    loadB(Ba, ea, 0);
    for (int ch = 0; ch < 32; ch += 2) {
        loadB(Bb, eb, ch + 1);
        proc(Ba, ea, ch);
        if (ch + 2 < 32) loadB(Ba, ea, ch + 2);
        proc(Bb, eb, ch + 1);
    }

    // ---- unpack winner, cross-lane top-2 merge over the 16 cols ----
    int kidx[4][4];
    #pragma unroll
    for (int s = 0; s < 4; ++s)
        #pragma unroll
        for (int r = 0; r < 4; ++r) {
            int ch = 31 - (int)(__float_as_uint(best[s][r]) & 31u);
            kidx[s][r] = (ch << 4) | n;
        }
    #pragma unroll
    for (int off = 1; off <= 8; off <<= 1) {
        #pragma unroll
        for (int s = 0; s < 4; ++s)
            #pragma unroll
            for (int r = 0; r < 4; ++r) {
                float ob = __shfl_xor(best[s][r], off);
                float os = __shfl_xor(sec[s][r], off);
                int   ok = __shfl_xor(kidx[s][r], off);
                float mn = fminf(best[s][r], ob);
                sec[s][r] = fmaxf(fmaxf(sec[s][r], os), mn);
                bool take = (ob > best[s][r]) || (ob == best[s][r] && ok < kidx[s][r]);
                best[s][r] = take ? ob : best[s][r];
                kidx[s][r] = take ? ok : kidx[s][r];
            }
    }

    // dist = x2 - 2*score (masked score err ~32ulp, << loss threshold)
    float lossd[4][4];
    #pragma unroll
    for (int s = 0; s < 4; ++s)
        #pragma unroll
        for (int r = 0; r < 4; ++r)
            lossd[s][r] = fmaf(-2.f, best[s][r], x2c[s][r]);

    // ---- rare fp64 certify/rescan for thin-margin rows ----
    #pragma unroll
    for (int s = 0; s < 4; ++s)
        for (int r = 0; r < 4; ++r) {
            unsigned long long m =
                __ballot((best[s][r] - sec[s][r] < TAU_S) && (n == 0));
            while (m) {
                int l = __builtin_ctzll(m);
                m &= m - 1;
                int qq = l >> 4;
                double bd; int bk;
                wave_rescan(x, e, wbase + s * 16 + 4 * qq + r, &bd, &bk);
                if (q == qq) { lossd[s][r] = (float)bd; kidx[s][r] = bk; }
            }
        }

    // ---- write quantized rows + per-block loss (r17: 1 atomic/block) ----
    float lp = 0.f;
    #pragma unroll
    for (int s = 0; s < 4; ++s)
        #pragma unroll
        for (int r = 0; r < 4; ++r) {
            int row = wbase + s * 16 + 4 * q + r;
            const float4* src = (const float4*)(eT + (size_t)kidx[s][r] * DIM);
            ((float4*)(out + (size_t)row * DIM))[n] = src[n];
            if (n == 0) lp += lossd[s][r];
        }
    #pragma unroll
    for (int off = 1; off < 64; off <<= 1) lp += __shfl_xor(lp, off);
    if (lane == 0) lred[wav] = lp;
    __syncthreads();
    if (tid == 0)
        atomicAdd(loss_slot, (lred[0] + lred[1] + lred[2] + lred[3]) *
                             (1.25f / ((float)N_ROWS * (float)DIM)));
}

// ---- fallback (no workspace): round-3 scalar kernel, 2 rows/thread ---------
__global__ __launch_bounds__(256, 2) void vq_scalar(
    const float* __restrict__ x, const float* __restrict__ e,
    float* __restrict__ out, float* __restrict__ loss_slot) {

    __shared__ float sh[128 * 68];
    __shared__ float red[256];
    const int tid = threadIdx.x;
    const int blockBase = blockIdx.x * 512;
    const int r0 = blockBase + tid, r1 = r0 + 256;

    float xa[DIM], xb[DIM];
    {
        const float4* xr0 = (const float4*)(x + (size_t)r0 * DIM);
        const float4* xr1 = (const float4*)(x + (size_t)r1 * DIM);
        #pragma unroll
        for (int j = 0; j < 16; ++j) {
            float4 v0 = xr0[j], v1 = xr1[j];
            xa[4*j]=v0.x; xa[4*j+1]=v0.y; xa[4*j+2]=v0.z; xa[4*j+3]=v0.w;
            xb[4*j]=v1.x; xb[4*j+1]=v1.y; xb[4*j+2]=v1.z; xb[4*j+3]=v1.w;
        }
    }
    float x2a = 0.f, x2b = 0.f;
    #pragma unroll
    for (int d = 0; d < DIM; ++d) { x2a = fmaf(xa[d], xa[d], x2a); x2b = fmaf(xb[d], xb[d], x2b); }

    float bestA = 3.4e38f, secA = 3.4e38f, bestB = 3.4e38f, secB = 3.4e38f;
    int bkA = 0, bkB = 0;

    for (int kb = 0; kb < KCODES; kb += 128) {
        for (int idx = tid; idx < 128 * DIM; idx += 256) {
            int d = idx >> 7, c = idx & 127;
            sh[c * 68 + d] = e[d * KCODES + kb + c];
        }
        __syncthreads();
        if (tid < 128) {
            float ssum = 0.f;
            for (int d = 0; d < DIM; ++d) { float v = sh[tid * 68 + d]; ssum = fmaf(v, v, ssum); }
            sh[tid * 68 + 64] = ssum;
        }
        __syncthreads();
        for (int k = 0; k < 128; ++k) {
            const float* ck = sh + k * 68;
            float a0=0.f,a1=0.f,b0=0.f,b1=0.f;
            #pragma unroll
            for (int j = 0; j < 16; j += 2) {
                float4 c0 = *(const float4*)(ck + 4*j);
                float4 c1 = *(const float4*)(ck + 4*j + 4);
                a0=fmaf(xa[4*j],c0.x,a0); a0=fmaf(xa[4*j+1],c0.y,a0); a0=fmaf(xa[4*j+2],c0.z,a0); a0=fmaf(xa[4*j+3],c0.w,a0);
                b0=fmaf(xb[4*j],c0.x,b0); b0=fmaf(xb[4*j+1],c0.y,b0); b0=fmaf(xb[4*j+2],c0.z,b0); b0=fmaf(xb[4*j+3],c0.w,b0);
                a1=fmaf(xa[4*j+4],c1.x,a1); a1=fmaf(xa[4*j+5],c1.y,a1); a1=fmaf(xa[4*j+6],c1.z,a1); a1=fmaf(xa[4*j+7],c1.w,a1);
                b1=fmaf(xb[4*j+4],c1.x,b1); b1=fmaf(xb[4*j+5],c1.y,b1); b1=fmaf(xb[4*j+6],c1.z,b1); b1=fmaf(xb[4*j+7],c1.w,b1);
            }
            const float e2k = ck[64]; const int kg = kb + k;
            const float dA = fmaf(-2.f, a0 + a1, x2a + e2k);
            const float dB = fmaf(-2.f, b0 + b1, x2b + e2k);
            if (dA < bestA) { secA = bestA; bestA = dA; bkA = kg; } else if (dA < secA) secA = dA;
            if (dB < bestB) { secB = bestB; bestB = dB; bkB = kg; } else if (dB < secB) secB = dB;
        }
        __syncthreads();
    }

    const int lane = tid & 63;
    const int waveBase = blockBase + (tid & ~63);
    unsigned long long m = __ballot(secA - bestA < TAU_SC);
    while (m) {
        int l = __builtin_ctzll(m); m &= m - 1;
        double bd; int bk2;
        wave_rescan(x, e, waveBase + l, &bd, &bk2);
        if (lane == l) { bestA = (float)bd; bkA = bk2; }
    }
    m = __ballot(secB - bestB < TAU_SC);
    while (m) {
        int l = __builtin_ctzll(m); m &= m - 1;
        double bd; int bk2;
        wave_rescan(x, e, waveBase + 256 + l, &bd, &bk2);
        if (lane == l) { bestB = (float)bd; bkB = bk2; }
    }

    float4* o0 = (float4*)(out + (size_t)r0 * DIM);
    float4* o1 = (float4*)(out + (size_t)r1 * DIM);
    #pragma unroll
    for (int j = 0; j < 16; ++j) {
        float4 va, vb;
        va.x=e[(4*j)*KCODES+bkA]; vb.x=e[(4*j)*KCODES+bkB];
        va.y=e[(4*j+1)*KCODES+bkA]; vb.y=e[(4*j+1)*KCODES+bkB];
        va.z=e[(4*j+2)*KCODES+bkA]; vb.z=e[(4*j+2)*KCODES+bkB];
        va.w=e[(4*j+3)*KCODES+bkA]; vb.w=e[(4*j+3)*KCODES+bkB];
        o0[j]=va; o1[j]=vb;
    }

    red[tid] = bestA + bestB;
    __syncthreads();
    #pragma unroll
    for (int s2 = 128; s2 > 0; s2 >>= 1) {
        if (tid < s2) red[tid] += red[tid + s2];
        __syncthreads();
    }
    if (tid == 0) atomicAdd(loss_slot, red[0] * (1.25f / ((float)N_ROWS * (float)DIM)));
}

extern "C" void kernel_launch(void* const* d_in, const int* in_sizes, int n_in,
                              void* d_out, int out_size, void* d_ws, size_t ws_size,
                              hipStream_t stream) {
    const float* x = (const float*)d_in[0];   // [N, D]
    const float* e = (const float*)d_in[1];   // [D, K]
    float* out = (float*)d_out;               // N*D quantized + 1 loss
    float* loss_slot = out + (size_t)N_ROWS * DIM;

    // ws: eT f32 @0 (131072) | Bc bf16 @131072 (131072) | e2h @262144 (2048)
    const size_t ws_needed = 131072 + 131072 + 2048;

    if (ws_size >= ws_needed) {
        float* eT = (float*)d_ws;
        short* Bc = (short*)((char*)d_ws + 131072);
        float* e2h = (float*)((char*)d_ws + 262144);
        vq_init<<<128, 256, 0, stream>>>(e, eT, Bc, e2h, loss_slot);
        vq_mfma<<<N_ROWS / 256, 256, 0, stream>>>(x, e, eT, Bc, e2h, out, loss_slot);
    } else {
        vq_zero_loss<<<1, 1, 0, stream>>>(loss_slot);
        vq_scalar<<<N_ROWS / 512, 256, 0, stream>>>(x, e, out, loss_slot);
    }
}

// Round 18
// 201.494 us; speedup vs baseline: 1.9329x; 1.1024x over previous
//
#include <hip/hip_runtime.h>

#define N_ROWS 262144
#define DIM 64
#define KCODES 512
#define TAU_S  1.2e-3f  // r18: single change vs r17 (was 2.5e-3). Margin-of-two-
                        // scores err bound ~3.4e-4 (lo*lo 1.3e-4/score + mask
                        // 3e-5 + f32 accum 1e-5) -> 3.5x margin retained.
#define TAU_SC 4e-3f    // scalar fallback (round-3 proven)

typedef __attribute__((ext_vector_type(8))) short bf16x8;
typedef __attribute__((ext_vector_type(4))) float f32x4;

static __device__ __forceinline__ short f2bf(float f) {   // RNE float->bf16
    union { float f; unsigned u; } c; c.f = f;
    unsigned r = (c.u + 0x7fff + ((c.u >> 16) & 1)) >> 16;
    return (short)r;
}
static __device__ __forceinline__ float bf2f(short b) {
    union { float f; unsigned u; } c;
    c.u = ((unsigned)(unsigned short)b) << 16;
    return c.f;
}

// ---- init ------------------------------------------------------------------
// eT  f32 [K][D]                       (exact output gather)
// Bc  bf16 chunk-part-major: [ch][part][n][q][j] shorts,
//     part: 0=hi d0..31, 1=hi d32..63, 2=lo d0..31, 3=lo d32..63
//     index = ch*2048 + part*512 + n*32 + q*8 + j   (per-part wave load = 1KB contig)
// e2h f32 [K] = -0.5*||e_k||^2 (fp64-accurate)
__global__ void vq_init(const float* __restrict__ e, float* __restrict__ eT,
                        short* __restrict__ Bc, float* __restrict__ e2h,
                        float* __restrict__ loss_slot) {
    int idx = blockIdx.x * 256 + threadIdx.x;   // grid covers 32768
    if (idx < KCODES * DIM) {
        int k = idx >> 6, d = idx & 63;
        float v = e[d * KCODES + k];
        eT[k * DIM + d] = v;
        short hi = f2bf(v);
        short lo = f2bf(v - bf2f(hi));          // hi-residual, then RNE to bf16
        int ch = k >> 4, n = k & 15, q = (d >> 3) & 3, j = d & 7, half = d >> 5;
        Bc[ch * 2048 + (half)     * 512 + n * 32 + q * 8 + j] = hi;
        Bc[ch * 2048 + (2 + half) * 512 + n * 32 + q * 8 + j] = lo;
    }
    if (idx < KCODES) {
        double s = 0.0;
        for (int d = 0; d < DIM; ++d) {
            double v = (double)e[d * KCODES + idx];
            s = fma(v, v, s);
        }
        e2h[idx] = (float)(-0.5 * s);
    }
    if (idx == 0) *loss_slot = 0.f;
}

__global__ void vq_zero_loss(float* __restrict__ loss_slot) { *loss_slot = 0.f; }

// ---- wave-cooperative exact fp64 rescan of one row (all 64 lanes call) -----
__device__ inline void wave_rescan(const float* __restrict__ x,
                                   const float* __restrict__ e,  // [D][K]
                                   int row, double* outDist, int* outK) {
    const int lane = threadIdx.x & 63;
    const float* xr = x + (size_t)row * DIM;
    double x2d = 0.0;
    for (int d = 0; d < DIM; ++d) {
        double xd = (double)xr[d];
        x2d = fma(xd, xd, x2d);
    }
    double best = 1e300; int bk = 0;
    for (int j = 0; j < 8; ++j) {
        const int k = lane + (j << 6);
        double dot = 0.0, e2 = 0.0;
        for (int d = 0; d < DIM; ++d) {
            double xd = (double)xr[d];
            double ev = (double)e[d * KCODES + k];
            dot = fma(xd, ev, dot);
            e2 = fma(ev, ev, e2);
        }
        double dist = fma(-2.0, dot, x2d + e2);
        if (dist < best) { best = dist; bk = k; }
    }
    #pragma unroll
    for (int off = 32; off; off >>= 1) {
        double od = __shfl_xor(best, off);
        int ok = __shfl_xor(bk, off);
        if (od < best || (od == best && ok < bk)) { best = od; bk = ok; }
    }
    *outDist = best; *outK = bk;
}

// ---- main: 64 rows/wave, global-B ping-pong, no hot-loop barriers ----------
// r18: r17 winner (143.6us kernel / 222us harness) + ONE change: TAU_S
// 2.5e-3 -> 1.2e-3. Tail model (two consecutive confirmed wins): dispatch
// time = mean wave work + straggler/drain tail; r15 (-15us, TAU 6e-3->2.5e-3)
// and r17 (-17us, 4096->1024 atomics) each converted a removed end-of-life
// serialization ~1:1 into dispatch time. Remaining tail = rescan population:
// flag rate ~2%/row at 2.5e-3 -> 73% of waves run >=1 rescan (~5-10us each).
// Flag rate depends ONLY on TAU vs the data's margin distribution, so
// tightening TAU is the only remaining lever. 1.2e-3 keeps 3.5x err margin.
// If delta <3us: rescan tail exhausted -> practical floor declared.
__global__ __launch_bounds__(256, 2) void vq_mfma(
    const float* __restrict__ x, const float* __restrict__ e,
    const float* __restrict__ eT, const short* __restrict__ Bc,
    const float* __restrict__ e2h,
    float* __restrict__ out, float* __restrict__ loss_slot) {

    __shared__ float she2[KCODES];     // 2 KB: -0.5*e2, staged once
    __shared__ float lred[4];          // per-wave loss partials (r17-proven)

    const int tid = threadIdx.x;
    const int lane = tid & 63;
    const int n = lane & 15;           // MFMA col (code within chunk) / A row
    const int q = lane >> 4;           // quad
    const int wav = tid >> 6;          // 0..3
    const int wbase = blockIdx.x * 256 + wav * 64;   // 64 rows per wave

    for (int i = tid; i < KCODES; i += 256) she2[i] = e2h[i];
    __syncthreads();

    // ---- A fragments (hi/lo) + C-layout x2 for 4 strips of 16 rows ----
    bf16x8 Ah0[4], Ah1[4], Al0[4], Al1[4];
    float x2c[4][4];
    #pragma unroll
    for (int s = 0; s < 4; ++s) {
        const int row = wbase + s * 16 + n;            // A-layout row = lane&15
        const float4* xr = (const float4*)(x + (size_t)row * DIM);
        float4 f0 = xr[2*q], f1 = xr[2*q+1], f2 = xr[8+2*q], f3 = xr[9+2*q];
        float v0s[8] = {f0.x,f0.y,f0.z,f0.w,f1.x,f1.y,f1.z,f1.w};   // dims 8q..
        float v1s[8] = {f2.x,f2.y,f2.z,f2.w,f3.x,f3.y,f3.z,f3.w};   // dims 32+8q..
        float p = 0.f;
        #pragma unroll
        for (int j = 0; j < 8; ++j) {
            float v0 = v0s[j], v1 = v1s[j];
            short h0 = f2bf(v0), h1 = f2bf(v1);
            Ah0[s][j] = h0;            Ah1[s][j] = h1;
            Al0[s][j] = f2bf(v0 - bf2f(h0));
            Al1[s][j] = f2bf(v1 - bf2f(h1));
            p = fmaf(v0, v0, p);
            p = fmaf(v1, v1, p);
        }
        p += __shfl_xor(p, 16);        // lanes {n,n+16,n+32,n+48} -> full x2
        p += __shfl_xor(p, 32);
        #pragma unroll
        for (int r = 0; r < 4; ++r)    // C-layout row 4q+r held by src lane 4q+r
            x2c[s][r] = __shfl(p, 4 * q + r);
    }

    float best[4][4], sec[4][4];
    #pragma unroll
    for (int s = 0; s < 4; ++s)
        #pragma unroll
        for (int r = 0; r < 4; ++r) { best[s][r] = -3.4e38f; sec[s][r] = -3.4e38f; }

    bf16x8 Ba[4], Bb[4];
    float ea, eb;

    auto loadB = [&](bf16x8* Bf, float& ev, int ch) {
        const short* bp = Bc + ch * 2048 + n * 32 + q * 8;
        Bf[0] = *(const bf16x8*)(bp);           // hi d0..31  (k = 8q+j)
        Bf[1] = *(const bf16x8*)(bp + 512);     // hi d32..63
        Bf[2] = *(const bf16x8*)(bp + 1024);    // lo d0..31
        Bf[3] = *(const bf16x8*)(bp + 1536);    // lo d32..63
        ev = she2[ch * 16 + n];                 // -0.5*e2 (16 banks, broadcast)
    };

    auto proc = [&](const bf16x8* Bf, float ev, int ch) {
        const unsigned chid = 31u - (unsigned)ch;   // bigger = earlier chunk
        #pragma unroll
        for (int s = 0; s < 4; ++s) {
            f32x4 acc = {ev, ev, ev, ev};           // score = dot - 0.5*e2
            acc = __builtin_amdgcn_mfma_f32_16x16x32_bf16(Ah0[s], Bf[0], acc, 0, 0, 0);
            acc = __builtin_amdgcn_mfma_f32_16x16x32_bf16(Ah1[s], Bf[1], acc, 0, 0, 0);
            acc = __builtin_amdgcn_mfma_f32_16x16x32_bf16(Ah0[s], Bf[2], acc, 0, 0, 0);
            acc = __builtin_amdgcn_mfma_f32_16x16x32_bf16(Ah1[s], Bf[3], acc, 0, 0, 0);
            acc = __builtin_amdgcn_mfma_f32_16x16x32_bf16(Al0[s], Bf[0], acc, 0, 0, 0);
            acc = __builtin_amdgcn_mfma_f32_16x16x32_bf16(Al1[s], Bf[1], acc, 0, 0, 0);
            // lo*lo dropped: |err| ~1.3e-4 << TAU_S margin, certified below
            #pragma unroll
            for (int r = 0; r < 4; ++r) {
                unsigned kb = (__float_as_uint(acc[r]) & 0xFFFFFFE0u) | chid;
                float key = __uint_as_float(kb);
                float mn = fminf(best[s][r], key);
                sec[s][r] = fmaxf(sec[s][r], mn);
                best[s][r] = fmaxf(best[s][r], key);
            }
        }
    };

    // ping-pong global (L2-hot) prefetch over 32 chunks of 16 codes
    loadB(Ba, ea, 0);
    for (int ch = 0; ch < 32; ch += 2) {
        loadB(Bb, eb, ch + 1);
        proc(Ba, ea, ch);
        if (ch + 2 < 32) loadB(Ba, ea, ch + 2);
        proc(Bb, eb, ch + 1);
    }

    // ---- unpack winner, cross-lane top-2 merge over the 16 cols ----
    int kidx[4][4];
    #pragma unroll
    for (int s = 0; s < 4; ++s)
        #pragma unroll
        for (int r = 0; r < 4; ++r) {
            int ch = 31 - (int)(__float_as_uint(best[s][r]) & 31u);
            kidx[s][r] = (ch << 4) | n;
        }
    #pragma unroll
    for (int off = 1; off <= 8; off <<= 1) {
        #pragma unroll
        for (int s = 0; s < 4; ++s)
            #pragma unroll
            for (int r = 0; r < 4; ++r) {
                float ob = __shfl_xor(best[s][r], off);
                float os = __shfl_xor(sec[s][r], off);
                int   ok = __shfl_xor(kidx[s][r], off);
                float mn = fminf(best[s][r], ob);
                sec[s][r] = fmaxf(fmaxf(sec[s][r], os), mn);
                bool take = (ob > best[s][r]) || (ob == best[s][r] && ok < kidx[s][r]);
                best[s][r] = take ? ob : best[s][r];
                kidx[s][r] = take ? ok : kidx[s][r];
            }
    }

    // dist = x2 - 2*score (masked score err ~32ulp, << loss threshold)
    float lossd[4][4];
    #pragma unroll
    for (int s = 0; s < 4; ++s)
        #pragma unroll
        for (int r = 0; r < 4; ++r)
            lossd[s][r] = fmaf(-2.f, best[s][r], x2c[s][r]);

    // ---- rare fp64 certify/rescan for thin-margin rows ----
    #pragma unroll
    for (int s = 0; s < 4; ++s)
        for (int r = 0; r < 4; ++r) {
            unsigned long long m =
                __ballot((best[s][r] - sec[s][r] < TAU_S) && (n == 0));
            while (m) {
                int l = __builtin_ctzll(m);
                m &= m - 1;
                int qq = l >> 4;
                double bd; int bk;
                wave_rescan(x, e, wbase + s * 16 + 4 * qq + r, &bd, &bk);
                if (q == qq) { lossd[s][r] = (float)bd; kidx[s][r] = bk; }
            }
        }

    // ---- write quantized rows + per-block loss (1 atomic/block, r17-proven) ----
    float lp = 0.f;
    #pragma unroll
    for (int s = 0; s < 4; ++s)
        #pragma unroll
        for (int r = 0; r < 4; ++r) {
            int row = wbase + s * 16 + 4 * q + r;
            const float4* src = (const float4*)(eT + (size_t)kidx[s][r] * DIM);
            ((float4*)(out + (size_t)row * DIM))[n] = src[n];
            if (n == 0) lp += lossd[s][r];
        }
    #pragma unroll
    for (int off = 1; off < 64; off <<= 1) lp += __shfl_xor(lp, off);
    if (lane == 0) lred[wav] = lp;
    __syncthreads();
    if (tid == 0)
        atomicAdd(loss_slot, (lred[0] + lred[1] + lred[2] + lred[3]) *
                             (1.25f / ((float)N_ROWS * (float)DIM)));
}

// ---- fallback (no workspace): round-3 scalar kernel, 2 rows/thread ---------
__global__ __launch_bounds__(256, 2) void vq_scalar(
    const float* __restrict__ x, const float* __restrict__ e,
    float* __restrict__ out, float* __restrict__ loss_slot) {

    __shared__ float sh[128 * 68];
    __shared__ float red[256];
    const int tid = threadIdx.x;
    const int blockBase = blockIdx.x * 512;
    const int r0 = blockBase + tid, r1 = r0 + 256;

    float xa[DIM], xb[DIM];
    {
        const float4* xr0 = (const float4*)(x + (size_t)r0 * DIM);
        const float4* xr1 = (const float4*)(x + (size_t)r1 * DIM);
        #pragma unroll
        for (int j = 0; j < 16; ++j) {
            float4 v0 = xr0[j], v1 = xr1[j];
            xa[4*j]=v0.x; xa[4*j+1]=v0.y; xa[4*j+2]=v0.z; xa[4*j+3]=v0.w;
            xb[4*j]=v1.x; xb[4*j+1]=v1.y; xb[4*j+2]=v1.z; xb[4*j+3]=v1.w;
        }
    }
    float x2a = 0.f, x2b = 0.f;
    #pragma unroll
    for (int d = 0; d < DIM; ++d) { x2a = fmaf(xa[d], xa[d], x2a); x2b = fmaf(xb[d], xb[d], x2b); }

    float bestA = 3.4e38f, secA = 3.4e38f, bestB = 3.4e38f, secB = 3.4e38f;
    int bkA = 0, bkB = 0;

    for (int kb = 0; kb < KCODES; kb += 128) {
        for (int idx = tid; idx < 128 * DIM; idx += 256) {
            int d = idx >> 7, c = idx & 127;
            sh[c * 68 + d] = e[d * KCODES + kb + c];
        }
        __syncthreads();
        if (tid < 128) {
            float ssum = 0.f;
            for (int d = 0; d < DIM; ++d) { float v = sh[tid * 68 + d]; ssum = fmaf(v, v, ssum); }
            sh[tid * 68 + 64] = ssum;
        }
        __syncthreads();
        for (int k = 0; k < 128; ++k) {
            const float* ck = sh + k * 68;
            float a0=0.f,a1=0.f,b0=0.f,b1=0.f;
            #pragma unroll
            for (int j = 0; j < 16; j += 2) {
                float4 c0 = *(const float4*)(ck + 4*j);
                float4 c1 = *(const float4*)(ck + 4*j + 4);
                a0=fmaf(xa[4*j],c0.x,a0); a0=fmaf(xa[4*j+1],c0.y,a0); a0=fmaf(xa[4*j+2],c0.z,a0); a0=fmaf(xa[4*j+3],c0.w,a0);
                b0=fmaf(xb[4*j],c0.x,b0); b0=fmaf(xb[4*j+1],c0.y,b0); b0=fmaf(xb[4*j+2],c0.z,b0); b0=fmaf(xb[4*j+3],c0.w,b0);
                a1=fmaf(xa[4*j+4],c1.x,a1); a1=fmaf(xa[4*j+5],c1.y,a1); a1=fmaf(xa[4*j+6],c1.z,a1); a1=fmaf(xa[4*j+7],c1.w,a1);
                b1=fmaf(xb[4*j+4],c1.x,b1); b1=fmaf(xb[4*j+5],c1.y,b1); b1=fmaf(xb[4*j+6],c1.z,b1); b1=fmaf(xb[4*j+7],c1.w,b1);
            }
            const float e2k = ck[64]; const int kg = kb + k;
            const float dA = fmaf(-2.f, a0 + a1, x2a + e2k);
            const float dB = fmaf(-2.f, b0 + b1, x2b + e2k);
            if (dA < bestA) { secA = bestA; bestA = dA; bkA = kg; } else if (dA < secA) secA = dA;
            if (dB < bestB) { secB = bestB; bestB = dB; bkB = kg; } else if (dB < secB) secB = dB;
        }
        __syncthreads();
    }

    const int lane = tid & 63;
    const int waveBase = blockBase + (tid & ~63);
    unsigned long long m = __ballot(secA - bestA < TAU_SC);
    while (m) {
        int l = __builtin_ctzll(m); m &= m - 1;
        double bd; int bk2;
        wave_rescan(x, e, waveBase + l, &bd, &bk2);
        if (lane == l) { bestA = (float)bd; bkA = bk2; }
    }
    m = __ballot(secB - bestB < TAU_SC);
    while (m) {
        int l = __builtin_ctzll(m); m &= m - 1;
        double bd; int bk2;
        wave_rescan(x, e, waveBase + 256 + l, &bd, &bk2);
        if (lane == l) { bestB = (float)bd; bkB = bk2; }
    }

    float4* o0 = (float4*)(out + (size_t)r0 * DIM);
    float4* o1 = (float4*)(out + (size_t)r1 * DIM);
    #pragma unroll
    for (int j = 0; j < 16; ++j) {
        float4 va, vb;
        va.x=e[(4*j)*KCODES+bkA]; vb.x=e[(4*j)*KCODES+bkB];
        va.y=e[(4*j+1)*KCODES+bkA]; vb.y=e[(4*j+1)*KCODES+bkB];
        va.z=e[(4*j+2)*KCODES+bkA]; vb.z=e[(4*j+2)*KCODES+bkB];
        va.w=e[(4*j+3)*KCODES+bkA]; vb.w=e[(4*j+3)*KCODES+bkB];
        o0[j]=va; o1[j]=vb;
    }

    red[tid] = bestA + bestB;
    __syncthreads();
    #pragma unroll
    for (int s2 = 128; s2 > 0; s2 >>= 1) {
        if (tid < s2) red[tid] += red[tid + s2];
        __syncthreads();
    }
    if (tid == 0) atomicAdd(loss_slot, red[0] * (1.25f / ((float)N_ROWS * (float)DIM)));
}

extern "C" void kernel_launch(void* const* d_in, const int* in_sizes, int n_in,
                              void* d_out, int out_size, void* d_ws, size_t ws_size,
                              hipStream_t stream) {
    const float* x = (const float*)d_in[0];   // [N, D]
    const float* e = (const float*)d_in[1];   // [D, K]
    float* out = (float*)d_out;               // N*D quantized + 1 loss
    float* loss_slot = out + (size_t)N_ROWS * DIM;

    // ws: eT f32 @0 (131072) | Bc bf16 @131072 (131072) | e2h @262144 (2048)
    const size_t ws_needed = 131072 + 131072 + 2048;

    if (ws_size >= ws_needed) {
        float* eT = (float*)d_ws;
        short* Bc = (short*)((char*)d_ws + 131072);
        float* e2h = (float*)((char*)d_ws + 262144);
        vq_init<<<128, 256, 0, stream>>>(e, eT, Bc, e2h, loss_slot);
        vq_mfma<<<N_ROWS / 256, 256, 0, stream>>>(x, e, eT, Bc, e2h, out, loss_slot);
    } else {
        vq_zero_loss<<<1, 1, 0, stream>>>(loss_slot);
        vq_scalar<<<N_ROWS / 512, 256, 0, stream>>>(x, e, out, loss_slot);
    }
}

// Round 20
// 199.251 us; speedup vs baseline: 1.9547x; 1.0113x over previous
//
#include <hip/hip_runtime.h>

#define N_ROWS 262144
#define DIM 64
#define KCODES 512
#define TAU_S  6e-4f    // r19: single change vs r18 (was 1.2e-3). Worst-case
                        // margin err ~3.4e-4 -> 1.8x margin; actual errors
                        // (random-sign) far smaller -- 3 TAU levels passed
                        // with identical absmax on this fixed-seed data.
#define TAU_SC 4e-3f    // scalar fallback (round-3 proven)

typedef __attribute__((ext_vector_type(8))) short bf16x8;
typedef __attribute__((ext_vector_type(4))) float f32x4;

static __device__ __forceinline__ short f2bf(float f) {   // RNE float->bf16
    union { float f; unsigned u; } c; c.f = f;
    unsigned r = (c.u + 0x7fff + ((c.u >> 16) & 1)) >> 16;
    return (short)r;
}
static __device__ __forceinline__ float bf2f(short b) {
    union { float f; unsigned u; } c;
    c.u = ((unsigned)(unsigned short)b) << 16;
    return c.f;
}

// ---- init ------------------------------------------------------------------
// eT  f32 [K][D]                       (exact output gather)
// Bc  bf16 chunk-part-major: [ch][part][n][q][j] shorts,
//     part: 0=hi d0..31, 1=hi d32..63, 2=lo d0..31, 3=lo d32..63
//     index = ch*2048 + part*512 + n*32 + q*8 + j   (per-part wave load = 1KB contig)
// e2h f32 [K] = -0.5*||e_k||^2 (fp64-accurate)
__global__ void vq_init(const float* __restrict__ e, float* __restrict__ eT,
                        short* __restrict__ Bc, float* __restrict__ e2h,
                        float* __restrict__ loss_slot) {
    int idx = blockIdx.x * 256 + threadIdx.x;   // grid covers 32768
    if (idx < KCODES * DIM) {
        int k = idx >> 6, d = idx & 63;
        float v = e[d * KCODES + k];
        eT[k * DIM + d] = v;
        short hi = f2bf(v);
        short lo = f2bf(v - bf2f(hi));          // hi-residual, then RNE to bf16
        int ch = k >> 4, n = k & 15, q = (d >> 3) & 3, j = d & 7, half = d >> 5;
        Bc[ch * 2048 + (half)     * 512 + n * 32 + q * 8 + j] = hi;
        Bc[ch * 2048 + (2 + half) * 512 + n * 32 + q * 8 + j] = lo;
    }
    if (idx < KCODES) {
        double s = 0.0;
        for (int d = 0; d < DIM; ++d) {
            double v = (double)e[d * KCODES + idx];
            s = fma(v, v, s);
        }
        e2h[idx] = (float)(-0.5 * s);
    }
    if (idx == 0) *loss_slot = 0.f;
}

__global__ void vq_zero_loss(float* __restrict__ loss_slot) { *loss_slot = 0.f; }

// ---- wave-cooperative exact fp64 rescan of one row (all 64 lanes call) -----
__device__ inline void wave_rescan(const float* __restrict__ x,
                                   const float* __restrict__ e,  // [D][K]
                                   int row, double* outDist, int* outK) {
    const int lane = threadIdx.x & 63;
    const float* xr = x + (size_t)row * DIM;
    double x2d = 0.0;
    for (int d = 0; d < DIM; ++d) {
        double xd = (double)xr[d];
        x2d = fma(xd, xd, x2d);
    }
    double best = 1e300; int bk = 0;
    for (int j = 0; j < 8; ++j) {
        const int k = lane + (j << 6);
        double dot = 0.0, e2 = 0.0;
        for (int d = 0; d < DIM; ++d) {
            double xd = (double)xr[d];
            double ev = (double)e[d * KCODES + k];
            dot = fma(xd, ev, dot);
            e2 = fma(ev, ev, e2);
        }
        double dist = fma(-2.0, dot, x2d + e2);
        if (dist < best) { best = dist; bk = k; }
    }
    #pragma unroll
    for (int off = 32; off; off >>= 1) {
        double od = __shfl_xor(best, off);
        int ok = __shfl_xor(bk, off);
        if (od < best || (od == best && ok < bk)) { best = od; bk = ok; }
    }
    *outDist = best; *outK = bk;
}

// ---- main: 64 rows/wave, global-B ping-pong, no hot-loop barriers ----------
// r19: r18 winner (127us kernel / 201us harness) + ONE change: TAU_S
// 1.2e-3 -> 6e-4. Tail model (three consecutive confirmed wins): dispatch
// time = issue work + rescan-straggler tail, tail ~linear in log(TAU):
// r15 (6e-3->2.5e-3): -15us; r17 (atomics/4): -17us; r18 (2.5->1.2e-3):
// -17us. Flag rate at 1.2e-3 ~1%/row -> 47% of waves rescan; 6e-4 -> ~27%.
// If absmax jumps or fail: margin exceeded, revert to r18. If delta <3us:
// tail exhausted, practical floor declared.
__global__ __launch_bounds__(256, 2) void vq_mfma(
    const float* __restrict__ x, const float* __restrict__ e,
    const float* __restrict__ eT, const short* __restrict__ Bc,
    const float* __restrict__ e2h,
    float* __restrict__ out, float* __restrict__ loss_slot) {

    __shared__ float she2[KCODES];     // 2 KB: -0.5*e2, staged once
    __shared__ float lred[4];          // per-wave loss partials (r17-proven)

    const int tid = threadIdx.x;
    const int lane = tid & 63;
    const int n = lane & 15;           // MFMA col (code within chunk) / A row
    const int q = lane >> 4;           // quad
    const int wav = tid >> 6;          // 0..3
    const int wbase = blockIdx.x * 256 + wav * 64;   // 64 rows per wave

    for (int i = tid; i < KCODES; i += 256) she2[i] = e2h[i];
    __syncthreads();

    // ---- A fragments (hi/lo) + C-layout x2 for 4 strips of 16 rows ----
    bf16x8 Ah0[4], Ah1[4], Al0[4], Al1[4];
    float x2c[4][4];
    #pragma unroll
    for (int s = 0; s < 4; ++s) {
        const int row = wbase + s * 16 + n;            // A-layout row = lane&15
        const float4* xr = (const float4*)(x + (size_t)row * DIM);
        float4 f0 = xr[2*q], f1 = xr[2*q+1], f2 = xr[8+2*q], f3 = xr[9+2*q];
        float v0s[8] = {f0.x,f0.y,f0.z,f0.w,f1.x,f1.y,f1.z,f1.w};   // dims 8q..
        float v1s[8] = {f2.x,f2.y,f2.z,f2.w,f3.x,f3.y,f3.z,f3.w};   // dims 32+8q..
        float p = 0.f;
        #pragma unroll
        for (int j = 0; j < 8; ++j) {
            float v0 = v0s[j], v1 = v1s[j];
            short h0 = f2bf(v0), h1 = f2bf(v1);
            Ah0[s][j] = h0;            Ah1[s][j] = h1;
            Al0[s][j] = f2bf(v0 - bf2f(h0));
            Al1[s][j] = f2bf(v1 - bf2f(h1));
            p = fmaf(v0, v0, p);
            p = fmaf(v1, v1, p);
        }
        p += __shfl_xor(p, 16);        // lanes {n,n+16,n+32,n+48} -> full x2
        p += __shfl_xor(p, 32);
        #pragma unroll
        for (int r = 0; r < 4; ++r)    // C-layout row 4q+r held by src lane 4q+r
            x2c[s][r] = __shfl(p, 4 * q + r);
    }

    float best[4][4], sec[4][4];
    #pragma unroll
    for (int s = 0; s < 4; ++s)
        #pragma unroll
        for (int r = 0; r < 4; ++r) { best[s][r] = -3.4e38f; sec[s][r] = -3.4e38f; }

    bf16x8 Ba[4], Bb[4];
    float ea, eb;

    auto loadB = [&](bf16x8* Bf, float& ev, int ch) {
        const short* bp = Bc + ch * 2048 + n * 32 + q * 8;
        Bf[0] = *(const bf16x8*)(bp);           // hi d0..31  (k = 8q+j)
        Bf[1] = *(const bf16x8*)(bp + 512);     // hi d32..63
        Bf[2] = *(const bf16x8*)(bp + 1024);    // lo d0..31
        Bf[3] = *(const bf16x8*)(bp + 1536);    // lo d32..63
        ev = she2[ch * 16 + n];                 // -0.5*e2 (16 banks, broadcast)
    };

    auto proc = [&](const bf16x8* Bf, float ev, int ch) {
        const unsigned chid = 31u - (unsigned)ch;   // bigger = earlier chunk
        #pragma unroll
        for (int s = 0; s < 4; ++s) {
            f32x4 acc = {ev, ev, ev, ev};           // score = dot - 0.5*e2
            acc = __builtin_amdgcn_mfma_f32_16x16x32_bf16(Ah0[s], Bf[0], acc, 0, 0, 0);
            acc = __builtin_amdgcn_mfma_f32_16x16x32_bf16(Ah1[s], Bf[1], acc, 0, 0, 0);
            acc = __builtin_amdgcn_mfma_f32_16x16x32_bf16(Ah0[s], Bf[2], acc, 0, 0, 0);
            acc = __builtin_amdgcn_mfma_f32_16x16x32_bf16(Ah1[s], Bf[3], acc, 0, 0, 0);
            acc = __builtin_amdgcn_mfma_f32_16x16x32_bf16(Al0[s], Bf[0], acc, 0, 0, 0);
            acc = __builtin_amdgcn_mfma_f32_16x16x32_bf16(Al1[s], Bf[1], acc, 0, 0, 0);
            // lo*lo dropped: |err| ~1.3e-4, certified below
            #pragma unroll
            for (int r = 0; r < 4; ++r) {
                unsigned kb = (__float_as_uint(acc[r]) & 0xFFFFFFE0u) | chid;
                float key = __uint_as_float(kb);
                float mn = fminf(best[s][r], key);
                sec[s][r] = fmaxf(sec[s][r], mn);
                best[s][r] = fmaxf(best[s][r], key);
            }
        }
    };

    // ping-pong global (L2-hot) prefetch over 32 chunks of 16 codes
    loadB(Ba, ea, 0);
    for (int ch = 0; ch < 32; ch += 2) {
        loadB(Bb, eb, ch + 1);
        proc(Ba, ea, ch);
        if (ch + 2 < 32) loadB(Ba, ea, ch + 2);
        proc(Bb, eb, ch + 1);
    }

    // ---- unpack winner, cross-lane top-2 merge over the 16 cols ----
    int kidx[4][4];
    #pragma unroll
    for (int s = 0; s < 4; ++s)
        #pragma unroll
        for (int r = 0; r < 4; ++r) {
            int ch = 31 - (int)(__float_as_uint(best[s][r]) & 31u);
            kidx[s][r] = (ch << 4) | n;
        }
    #pragma unroll
    for (int off = 1; off <= 8; off <<= 1) {
        #pragma unroll
        for (int s = 0; s < 4; ++s)
            #pragma unroll
            for (int r = 0; r < 4; ++r) {
                float ob = __shfl_xor(best[s][r], off);
                float os = __shfl_xor(sec[s][r], off);
                int   ok = __shfl_xor(kidx[s][r], off);
                float mn = fminf(best[s][r], ob);
                sec[s][r] = fmaxf(fmaxf(sec[s][r], os), mn);
                bool take = (ob > best[s][r]) || (ob == best[s][r] && ok < kidx[s][r]);
                best[s][r] = take ? ob : best[s][r];
                kidx[s][r] = take ? ok : kidx[s][r];
            }
    }

    // dist = x2 - 2*score (masked score err ~32ulp, << loss threshold)
    float lossd[4][4];
    #pragma unroll
    for (int s = 0; s < 4; ++s)
        #pragma unroll
        for (int r = 0; r < 4; ++r)
            lossd[s][r] = fmaf(-2.f, best[s][r], x2c[s][r]);

    // ---- rare fp64 certify/rescan for thin-margin rows ----
    #pragma unroll
    for (int s = 0; s < 4; ++s)
        for (int r = 0; r < 4; ++r) {
            unsigned long long m =
                __ballot((best[s][r] - sec[s][r] < TAU_S) && (n == 0));
            while (m) {
                int l = __builtin_ctzll(m);
                m &= m - 1;
                int qq = l >> 4;
                double bd; int bk;
                wave_rescan(x, e, wbase + s * 16 + 4 * qq + r, &bd, &bk);
                if (q == qq) { lossd[s][r] = (float)bd; kidx[s][r] = bk; }
            }
        }

    // ---- write quantized rows + per-block loss (1 atomic/block, r17-proven) ----
    float lp = 0.f;
    #pragma unroll
    for (int s = 0; s < 4; ++s)
        #pragma unroll
        for (int r = 0; r < 4; ++r) {
            int row = wbase + s * 16 + 4 * q + r;
            const float4* src = (const float4*)(eT + (size_t)kidx[s][r] * DIM);
            ((float4*)(out + (size_t)row * DIM))[n] = src[n];
            if (n == 0) lp += lossd[s][r];
        }
    #pragma unroll
    for (int off = 1; off < 64; off <<= 1) lp += __shfl_xor(lp, off);
    if (lane == 0) lred[wav] = lp;
    __syncthreads();
    if (tid == 0)
        atomicAdd(loss_slot, (lred[0] + lred[1] + lred[2] + lred[3]) *
                             (1.25f / ((float)N_ROWS * (float)DIM)));
}

// ---- fallback (no workspace): round-3 scalar kernel, 2 rows/thread ---------
__global__ __launch_bounds__(256, 2) void vq_scalar(
    const float* __restrict__ x, const float* __restrict__ e,
    float* __restrict__ out, float* __restrict__ loss_slot) {

    __shared__ float sh[128 * 68];
    __shared__ float red[256];
    const int tid = threadIdx.x;
    const int blockBase = blockIdx.x * 512;
    const int r0 = blockBase + tid, r1 = r0 + 256;

    float xa[DIM], xb[DIM];
    {
        const float4* xr0 = (const float4*)(x + (size_t)r0 * DIM);
        const float4* xr1 = (const float4*)(x + (size_t)r1 * DIM);
        #pragma unroll
        for (int j = 0; j < 16; ++j) {
            float4 v0 = xr0[j], v1 = xr1[j];
            xa[4*j]=v0.x; xa[4*j+1]=v0.y; xa[4*j+2]=v0.z; xa[4*j+3]=v0.w;
            xb[4*j]=v1.x; xb[4*j+1]=v1.y; xb[4*j+2]=v1.z; xb[4*j+3]=v1.w;
        }
    }
    float x2a = 0.f, x2b = 0.f;
    #pragma unroll
    for (int d = 0; d < DIM; ++d) { x2a = fmaf(xa[d], xa[d], x2a); x2b = fmaf(xb[d], xb[d], x2b); }

    float bestA = 3.4e38f, secA = 3.4e38f, bestB = 3.4e38f, secB = 3.4e38f;
    int bkA = 0, bkB = 0;

    for (int kb = 0; kb < KCODES; kb += 128) {
        for (int idx = tid; idx < 128 * DIM; idx += 256) {
            int d = idx >> 7, c = idx & 127;
            sh[c * 68 + d] = e[d * KCODES + kb + c];
        }
        __syncthreads();
        if (tid < 128) {
            float ssum = 0.f;
            for (int d = 0; d < DIM; ++d) { float v = sh[tid * 68 + d]; ssum = fmaf(v, v, ssum); }
            sh[tid * 68 + 64] = ssum;
        }
        __syncthreads();
        for (int k = 0; k < 128; ++k) {
            const float* ck = sh + k * 68;
            float a0=0.f,a1=0.f,b0=0.f,b1=0.f;
            #pragma unroll
            for (int j = 0; j < 16; j += 2) {
                float4 c0 = *(const float4*)(ck + 4*j);
                float4 c1 = *(const float4*)(ck + 4*j + 4);
                a0=fmaf(xa[4*j],c0.x,a0); a0=fmaf(xa[4*j+1],c0.y,a0); a0=fmaf(xa[4*j+2],c0.z,a0); a0=fmaf(xa[4*j+3],c0.w,a0);
                b0=fmaf(xb[4*j],c0.x,b0); b0=fmaf(xb[4*j+1],c0.y,b0); b0=fmaf(xb[4*j+2],c0.z,b0); b0=fmaf(xb[4*j+3],c0.w,b0);
                a1=fmaf(xa[4*j+4],c1.x,a1); a1=fmaf(xa[4*j+5],c1.y,a1); a1=fmaf(xa[4*j+6],c1.z,a1); a1=fmaf(xa[4*j+7],c1.w,a1);
                b1=fmaf(xb[4*j+4],c1.x,b1); b1=fmaf(xb[4*j+5],c1.y,b1); b1=fmaf(xb[4*j+6],c1.z,b1); b1=fmaf(xb[4*j+7],c1.w,b1);
            }
            const float e2k = ck[64]; const int kg = kb + k;
            const float dA = fmaf(-2.f, a0 + a1, x2a + e2k);
            const float dB = fmaf(-2.f, b0 + b1, x2b + e2k);
            if (dA < bestA) { secA = bestA; bestA = dA; bkA = kg; } else if (dA < secA) secA = dA;
            if (dB < bestB) { secB = bestB; bestB = dB; bkB = kg; } else if (dB < secB) secB = dB;
        }
        __syncthreads();
    }

    const int lane = tid & 63;
    const int waveBase = blockBase + (tid & ~63);
    unsigned long long m = __ballot(secA - bestA < TAU_SC);
    while (m) {
        int l = __builtin_ctzll(m); m &= m - 1;
        double bd; int bk2;
        wave_rescan(x, e, waveBase + l, &bd, &bk2);
        if (lane == l) { bestA = (float)bd; bkA = bk2; }
    }
    m = __ballot(secB - bestB < TAU_SC);
    while (m) {
        int l = __builtin_ctzll(m); m &= m - 1;
        double bd; int bk2;
        wave_rescan(x, e, waveBase + 256 + l, &bd, &bk2);
        if (lane == l) { bestB = (float)bd; bkB = bk2; }
    }

    float4* o0 = (float4*)(out + (size_t)r0 * DIM);
    float4* o1 = (float4*)(out + (size_t)r1 * DIM);
    #pragma unroll
    for (int j = 0; j < 16; ++j) {
        float4 va, vb;
        va.x=e[(4*j)*KCODES+bkA]; vb.x=e[(4*j)*KCODES+bkB];
        va.y=e[(4*j+1)*KCODES+bkA]; vb.y=e[(4*j+1)*KCODES+bkB];
        va.z=e[(4*j+2)*KCODES+bkA]; vb.z=e[(4*j+2)*KCODES+bkB];
        va.w=e[(4*j+3)*KCODES+bkA]; vb.w=e[(4*j+3)*KCODES+bkB];
        o0[j]=va; o1[j]=vb;
    }

    red[tid] = bestA + bestB;
    __syncthreads();
    #pragma unroll
    for (int s2 = 128; s2 > 0; s2 >>= 1) {
        if (tid < s2) red[tid] += red[tid + s2];
        __syncthreads();
    }
    if (tid == 0) atomicAdd(loss_slot, red[0] * (1.25f / ((float)N_ROWS * (float)DIM)));
}

extern "C" void kernel_launch(void* const* d_in, const int* in_sizes, int n_in,
                              void* d_out, int out_size, void* d_ws, size_t ws_size,
                              hipStream_t stream) {
    const float* x = (const float*)d_in[0];   // [N, D]
    const float* e = (const float*)d_in[1];   // [D, K]
    float* out = (float*)d_out;               // N*D quantized + 1 loss
    float* loss_slot = out + (size_t)N_ROWS * DIM;

    // ws: eT f32 @0 (131072) | Bc bf16 @131072 (131072) | e2h @262144 (2048)
    const size_t ws_needed = 131072 + 131072 + 2048;

    if (ws_size >= ws_needed) {
        float* eT = (float*)d_ws;
        short* Bc = (short*)((char*)d_ws + 131072);
        float* e2h = (float*)((char*)d_ws + 262144);
        vq_init<<<128, 256, 0, stream>>>(e, eT, Bc, e2h, loss_slot);
        vq_mfma<<<N_ROWS / 256, 256, 0, stream>>>(x, e, eT, Bc, e2h, out, loss_slot);
    } else {
        vq_zero_loss<<<1, 1, 0, stream>>>(loss_slot);
        vq_scalar<<<N_ROWS / 512, 256, 0, stream>>>(x, e, out, loss_slot);
    }
}